// Round 13
// baseline (114.313 us; speedup 1.0000x reference)
//
#include <hip/hip_runtime.h>
#include <math.h>

#define N_TOK 1024
#define C_DIM 384
#define H_NUM 12
#define PCOLS 1024
#define Q0 0
#define K0 192
#define V0 384
#define QP0 576
#define KP0 720
#define VP0 864
#define ATT_W 240
#define COEF 0.11785113019775792f   // 0.5*sqrt(2/36)
#define ISD 0.25f
#define CC2 (COEF * ISD)            // 0.029462...
#define KVG_ROWS 64                 // global KV' rows per head (57 used + pad)
#define LDS_ROWS 58                 // staged rows (29 K' + 28 V' + 1 pad)
#define TJ 128
#define NZ 4

// ---------- pack 6 weight mats into Wall[384][1024] (cols 1008..1023 zero) ----------
__global__ __launch_bounds__(256) void k_pack(
    const float* __restrict__ Wq, const float* __restrict__ Wk, const float* __restrict__ Wv,
    const float* __restrict__ Wqp, const float* __restrict__ Wkp, const float* __restrict__ Wvp,
    float* __restrict__ Wall)
{
    int t = blockIdx.x * 256 + threadIdx.x;
    int k = t >> 8;
    int col = (t & 255) * 4;
    float4 v;
    if (col < 192)       v = *(const float4*)(Wq  + k * 192 + col);
    else if (col < 384)  v = *(const float4*)(Wk  + k * 192 + col - 192);
    else if (col < 576)  v = *(const float4*)(Wv  + k * 192 + col - 384);
    else if (col < 720)  v = *(const float4*)(Wqp + k * 144 + col - 576);
    else if (col < 864)  v = *(const float4*)(Wkp + k * 144 + col - 720);
    else if (col < 1008) v = *(const float4*)(Wvp + k * 144 + col - 864);
    else                 v = make_float4(0.f, 0.f, 0.f, 0.f);
    *(float4*)(Wall + k * PCOLS + col) = v;
}

// ---------- proj GEMM: A global (prefetched 1 it ahead), B DMA-staged in LDS ----------
// grid (16,16), 256 thr (16 ty x 16 tx). Thread: 4 rows x 4 cols, BK=16.
__global__ __launch_bounds__(256) void k_proj(
    const float* __restrict__ x, const float* __restrict__ Wall, float* __restrict__ P)
{
    __shared__ float wsh[2][16 * 64];
    int tid = threadIdx.x;
    int lane = tid & 63, w = tid >> 6;
    int ty = tid >> 4, tx = tid & 15;
    int row0 = blockIdx.x * 64 + ty * 4;
    int col0 = blockIdx.y * 64;
    const float* xr = x + row0 * C_DIM;

    // wave w stages rows 4w..4w+3 of the 16x64 W-slice (1KB DMA)
#define STAGE_W(IT) do {                                                          \
        const float* src_ = Wall + ((IT) * 16 + w * 4 + (lane >> 4)) * PCOLS      \
                            + col0 + (lane & 15) * 4;                             \
        float* dst_ = wsh[(IT) & 1] + w * 256;                                    \
        __builtin_amdgcn_global_load_lds(                                         \
            (const __attribute__((address_space(1))) void*)src_,                  \
            (__attribute__((address_space(3))) void*)dst_, 16, 0, 0);             \
    } while (0)

    float4 A[4][4], An[4][4];
#pragma unroll
    for (int r = 0; r < 4; ++r)
#pragma unroll
        for (int q = 0; q < 4; ++q)
            A[r][q] = *(const float4*)(xr + r * C_DIM + q * 4);
    STAGE_W(0);
    __syncthreads();

    float acc[4][4] = {};
    for (int it = 0; it < 24; ++it) {
        if (it < 23) {
#pragma unroll
            for (int r = 0; r < 4; ++r)
#pragma unroll
                for (int q = 0; q < 4; ++q)
                    An[r][q] = *(const float4*)(xr + r * C_DIM + (it + 1) * 16 + q * 4);
            STAGE_W(it + 1);
        }
        const float* wb = wsh[it & 1];
#pragma unroll
        for (int q = 0; q < 4; ++q) {
#pragma unroll
            for (int u = 0; u < 4; ++u) {
                float4 b = *(const float4*)&wb[(q * 4 + u) * 64 + tx * 4];
#pragma unroll
                for (int r = 0; r < 4; ++r) {
                    float a = (u == 0) ? A[r][q].x : (u == 1) ? A[r][q].y
                             : (u == 2) ? A[r][q].z : A[r][q].w;
                    acc[r][0] = fmaf(a, b.x, acc[r][0]);
                    acc[r][1] = fmaf(a, b.y, acc[r][1]);
                    acc[r][2] = fmaf(a, b.z, acc[r][2]);
                    acc[r][3] = fmaf(a, b.w, acc[r][3]);
                }
            }
        }
        __syncthreads();
#pragma unroll
        for (int r = 0; r < 4; ++r)
#pragma unroll
            for (int q = 0; q < 4; ++q)
                A[r][q] = An[r][q];
    }
#pragma unroll
    for (int r = 0; r < 4; ++r)
        *(float4*)(P + (row0 + r) * PCOLS + col0 + tx * 4) =
            make_float4(acc[r][0], acc[r][1], acc[r][2], acc[r][3]);
}

// ---------- prep: build d-major Q'[h][29][1024], KV'[h][64][1024], qc[h][1024] ----------
__global__ __launch_bounds__(256) void k_prep(
    const float* __restrict__ P, const float* __restrict__ rot, const float* __restrict__ trans,
    float* __restrict__ KVg, float* __restrict__ Qg, float* __restrict__ qcg)
{
    __shared__ float kb[29 * 128];
    __shared__ float qb[29 * 128];
    __shared__ float vb[28 * 128];
    __shared__ float qcb[128];
    int h = blockIdx.y, nb = blockIdx.x;
    int tid = threadIdx.x;
    int nl = tid & 127, role = tid >> 7;
    int n = nb * 128 + nl;
    const float* R = rot + n * 9;
    float R00 = R[0], R01 = R[1], R02 = R[2];
    float R10 = R[3], R11 = R[4], R12 = R[5];
    float R20 = R[6], R21 = R[7], R22 = R[8];
    float t0 = trans[n * 3 + 0], t1 = trans[n * 3 + 1], t2 = trans[n * 3 + 2];

    if (role == 0) {
        const float* kr = P + n * PCOLS + K0 + h * 16;
#pragma unroll
        for (int d = 0; d < 16; ++d) kb[d * 128 + nl] = kr[d];
        const float* kp = P + n * PCOLS + KP0 + h * 12;
        float k2 = 0.f;
#pragma unroll
        for (int pt = 0; pt < 4; ++pt) {
            float p0 = kp[pt * 3 + 0], p1 = kp[pt * 3 + 1], p2 = kp[pt * 3 + 2];
            float g0 = R00 * p0 + R01 * p1 + R02 * p2 + t0;
            float g1 = R10 * p0 + R11 * p1 + R12 * p2 + t1;
            float g2 = R20 * p0 + R21 * p1 + R22 * p2 + t2;
            kb[(16 + pt * 3 + 0) * 128 + nl] = g0;
            kb[(16 + pt * 3 + 1) * 128 + nl] = g1;
            kb[(16 + pt * 3 + 2) * 128 + nl] = g2;
            k2 += g0 * g0 + g1 * g1 + g2 * g2;
        }
        kb[28 * 128 + nl] = -CC2 * k2;
    } else {
        const float* qr = P + n * PCOLS + Q0 + h * 16;
#pragma unroll
        for (int d = 0; d < 16; ++d) qb[d * 128 + nl] = qr[d] * ISD;
        const float* qp = P + n * PCOLS + QP0 + h * 12;
        float q2 = 0.f;
#pragma unroll
        for (int pt = 0; pt < 4; ++pt) {
            float p0 = qp[pt * 3 + 0], p1 = qp[pt * 3 + 1], p2 = qp[pt * 3 + 2];
            float g0 = R00 * p0 + R01 * p1 + R02 * p2 + t0;
            float g1 = R10 * p0 + R11 * p1 + R12 * p2 + t1;
            float g2 = R20 * p0 + R21 * p1 + R22 * p2 + t2;
            qb[(16 + pt * 3 + 0) * 128 + nl] = g0 * (2.f * CC2);
            qb[(16 + pt * 3 + 1) * 128 + nl] = g1 * (2.f * CC2);
            qb[(16 + pt * 3 + 2) * 128 + nl] = g2 * (2.f * CC2);
            q2 += g0 * g0 + g1 * g1 + g2 * g2;
        }
        qb[28 * 128 + nl] = 1.0f;
        qcb[nl] = fmaf(-CC2, q2, -4.0f);
        const float* vr = P + n * PCOLS + V0 + h * 16;
#pragma unroll
        for (int d = 0; d < 16; ++d) vb[d * 128 + nl] = vr[d];
        const float* vp = P + n * PCOLS + VP0 + h * 12;
#pragma unroll
        for (int pt = 0; pt < 4; ++pt) {
            float p0 = vp[pt * 3 + 0], p1 = vp[pt * 3 + 1], p2 = vp[pt * 3 + 2];
            vb[(16 + pt * 3 + 0) * 128 + nl] = R00 * p0 + R01 * p1 + R02 * p2 + t0;
            vb[(16 + pt * 3 + 1) * 128 + nl] = R10 * p0 + R11 * p1 + R12 * p2 + t1;
            vb[(16 + pt * 3 + 2) * 128 + nl] = R20 * p0 + R21 * p1 + R22 * p2 + t2;
        }
    }
    __syncthreads();

    for (int u = tid; u < 57 * 32; u += 256) {
        int d = u >> 5, c4 = u & 31;
        float4 v = (d < 29) ? *(float4*)&kb[d * 128 + c4 * 4]
                            : *(float4*)&vb[(d - 29) * 128 + c4 * 4];
        *(float4*)&KVg[(h * KVG_ROWS + d) * 1024 + nb * 128 + c4 * 4] = v;
    }
    for (int u = tid; u < 29 * 32; u += 256) {
        int d = u >> 5, c4 = u & 31;
        *(float4*)&Qg[(h * 29 + d) * 1024 + nb * 128 + c4 * 4] = *(float4*)&qb[d * 128 + c4 * 4];
    }
    if (tid < 32) *(float4*)&qcg[h * 1024 + nb * 128 + tid * 4] = *(float4*)&qcb[tid * 4];
}

// ---------- attention as register-tiled GEMM, 4q x 8k, TJ=128, DMA staging ----------
// 1-D grid 768, XCD-colocating remap. 256 thr: ty=tid>>4 (16 x 4q), tx=tid&15 (16 x 8k).
__global__ __launch_bounds__(256, 2) void k_attn(
    const float* __restrict__ KVg, const float* __restrict__ Qg,
    const float* __restrict__ qcg, float* __restrict__ part)
{
    __shared__ float Qs[29 * 64];
    __shared__ float KV[2][LDS_ROWS * TJ];
    int tid = threadIdx.x;
    int lane = tid & 63, w = tid >> 6;
    int ty = tid >> 4, tx = tid & 15;

    int bid = blockIdx.x;
    int xcd = bid & 7, slot = bid >> 3;
    int pair = xcd * 6 + (slot >> 4);     // 0..47
    int bx = slot & 15;
    int h = pair % H_NUM;
    int z = pair / H_NUM;

    int i0 = bx * 64;
    int jz0 = z * 256;
    const float* KVh = KVg + h * KVG_ROWS * 1024;

    for (int u = tid; u < 29 * 16; u += 256) {
        int d = u >> 4, c4 = u & 15;
        *(float4*)&Qs[d * 64 + c4 * 4] = *(const float4*)&Qg[(h * 29 + d) * 1024 + i0 + c4 * 4];
    }
    float qc[4];
#pragma unroll
    for (int r = 0; r < 4; ++r) qc[r] = qcg[h * 1024 + i0 + ty * 4 + r];

    // 29 DMA instrs per tile (rows 0..57, 2 rows each); waves issue {8,8,8,5}
    int nst = (w < 3) ? 8 : 5;
#define STAGE(T) do { float* buf_ = KV[(T) & 1]; int j0_ = jz0 + (T) * TJ;        \
        for (int m_ = 0; m_ < nst; ++m_) {                                        \
            int g_ = w * 8 + m_;                                                  \
            const float* src_ = KVh + (2 * g_ + (lane >> 5)) * 1024 + j0_ + (lane & 31) * 4; \
            float* dst_ = buf_ + g_ * 256;                                        \
            __builtin_amdgcn_global_load_lds(                                     \
                (const __attribute__((address_space(1))) void*)src_,              \
                (__attribute__((address_space(3))) void*)dst_, 16, 0, 0);         \
        } } while (0)

    STAGE(0);
    __syncthreads();

    float out[4][28] = {};
    float denom[4] = {};

    for (int t = 0; t < 2; ++t) {
        if (t < 1) STAGE(t + 1);
        const float* Kb = KV[t & 1];
        const float* Vb = Kb + 29 * TJ;

        float s[4][8] = {};
#pragma unroll
        for (int d = 0; d < 29; ++d) {
            float4 qv = *(const float4*)&Qs[d * 64 + ty * 4];
            float4 k0 = *(const float4*)&Kb[d * TJ + tx * 8];
            float4 k1 = *(const float4*)&Kb[d * TJ + tx * 8 + 4];
            float qa[4] = {qv.x, qv.y, qv.z, qv.w};
            float ka[8] = {k0.x, k0.y, k0.z, k0.w, k1.x, k1.y, k1.z, k1.w};
#pragma unroll
            for (int r = 0; r < 4; ++r)
#pragma unroll
                for (int j = 0; j < 8; ++j) s[r][j] = fmaf(qa[r], ka[j], s[r][j]);
        }

        float p[4][8];
#pragma unroll
        for (int r = 0; r < 4; ++r) {
#pragma unroll
            for (int j = 0; j < 8; ++j) {
                p[r][j] = __expf(s[r][j] + qc[r]);
                denom[r] += p[r][j];
            }
        }

#pragma unroll
        for (int d = 0; d < 28; ++d) {
            float4 v0 = *(const float4*)&Vb[d * TJ + tx * 8];
            float4 v1 = *(const float4*)&Vb[d * TJ + tx * 8 + 4];
            float va[8] = {v0.x, v0.y, v0.z, v0.w, v1.x, v1.y, v1.z, v1.w};
#pragma unroll
            for (int r = 0; r < 4; ++r) {
                float acc = out[r][d];
#pragma unroll
                for (int j = 0; j < 8; ++j) acc = fmaf(p[r][j], va[j], acc);
                out[r][d] = acc;
            }
        }
        __syncthreads();
    }

    // butterfly reduce across the 16 tx lanes (lane bits 0..3)
#pragma unroll
    for (int m = 1; m <= 8; m <<= 1) {
#pragma unroll
        for (int r = 0; r < 4; ++r) {
#pragma unroll
            for (int d = 0; d < 28; ++d) out[r][d] += __shfl_xor(out[r][d], m, 64);
            denom[r] += __shfl_xor(denom[r], m, 64);
        }
    }
    if (tx == 0) {
#pragma unroll
        for (int r = 0; r < 4; ++r) {
#pragma unroll
            for (int d = 0; d < 28; ++d) Qs[d * 64 + ty * 4 + r] = out[r][d];
            Qs[28 * 64 + ty * 4 + r] = denom[r];
        }
    }
    __syncthreads();
    for (int u = tid; u < 29 * 64; u += 256) {
        part[((z * H_NUM + h) * 29 + (u >> 6)) * N_TOK + i0 + (u & 63)] = Qs[u];
    }
}

// ---------- combine 4 partials, normalize, point-norm epilogue ----------
__global__ __launch_bounds__(256) void k_comb(
    const float* __restrict__ part, const float* __restrict__ rot,
    const float* __restrict__ trans, float* __restrict__ att)
{
    int t = blockIdx.x * 256 + threadIdx.x;
    int h = t >> 10, i = t & 1023;
    float v[29];
#pragma unroll
    for (int c = 0; c < 29; ++c) {
        float s = 0.f;
#pragma unroll
        for (int z = 0; z < NZ; ++z)
            s += part[((z * H_NUM + h) * 29 + c) * N_TOK + i];
        v[c] = s;
    }
    float inv = 1.f / v[28];
    float* arow = att + i * ATT_W;
#pragma unroll
    for (int d = 0; d < 16; ++d) arow[h * 16 + d] = v[d] * inv;
    float t0 = trans[i * 3 + 0], t1 = trans[i * 3 + 1], t2v = trans[i * 3 + 2];
    const float* R = rot + i * 9;
#pragma unroll
    for (int p = 0; p < 4; ++p) {
        float c0 = v[16 + p * 3 + 0] * inv - t0;
        float c1 = v[16 + p * 3 + 1] * inv - t1;
        float c2 = v[16 + p * 3 + 2] * inv - t2v;
        float l0 = R[0] * c0 + R[3] * c1 + R[6] * c2;
        float l1 = R[1] * c0 + R[4] * c1 + R[7] * c2;
        float l2 = R[2] * c0 + R[5] * c1 + R[8] * c2;
        arow[192 + h * 4 + p] = sqrtf(l0 * l0 + l1 * l1 + l2 * l2);
    }
}

// ---------- out GEMM (r10 classic): LDS-staged, reg-prefetch, grid (16,6) ----------
__global__ __launch_bounds__(256) void k_out(
    const float* __restrict__ att, const float* __restrict__ Wout,
    const float* __restrict__ bout, float* __restrict__ out)
{
    __shared__ float xs[64][17];
    __shared__ float wsh[16][64];
    int tid = threadIdx.x;
    int i0 = blockIdx.x * 64, c0 = blockIdx.y * 64;
    int lr = tid >> 2, lk = (tid & 3) * 4;
    int wr = tid >> 4, wc = (tid & 15) * 4;
    int ty = tid >> 4, tx = tid & 15;

    float4 xa = *(const float4*)(att + (i0 + lr) * ATT_W + lk);
    float4 wa = *(const float4*)(Wout + wr * C_DIM + c0 + wc);
    float acc[4][4] = {};

    for (int it = 0; it < 15; ++it) {
        xs[lr][lk + 0] = xa.x; xs[lr][lk + 1] = xa.y;
        xs[lr][lk + 2] = xa.z; xs[lr][lk + 3] = xa.w;
        *(float4*)&wsh[wr][wc] = wa;
        __syncthreads();
        if (it < 14) {
            xa = *(const float4*)(att + (i0 + lr) * ATT_W + (it + 1) * 16 + lk);
            wa = *(const float4*)(Wout + ((it + 1) * 16 + wr) * C_DIM + c0 + wc);
        }
#pragma unroll
        for (int kk = 0; kk < 16; ++kk) {
            float4 b = *(float4*)&wsh[kk][tx * 4];
            float a0 = xs[ty * 4 + 0][kk];
            float a1 = xs[ty * 4 + 1][kk];
            float a2 = xs[ty * 4 + 2][kk];
            float a3 = xs[ty * 4 + 3][kk];
            acc[0][0] = fmaf(a0, b.x, acc[0][0]); acc[0][1] = fmaf(a0, b.y, acc[0][1]);
            acc[0][2] = fmaf(a0, b.z, acc[0][2]); acc[0][3] = fmaf(a0, b.w, acc[0][3]);
            acc[1][0] = fmaf(a1, b.x, acc[1][0]); acc[1][1] = fmaf(a1, b.y, acc[1][1]);
            acc[1][2] = fmaf(a1, b.z, acc[1][2]); acc[1][3] = fmaf(a1, b.w, acc[1][3]);
            acc[2][0] = fmaf(a2, b.x, acc[2][0]); acc[2][1] = fmaf(a2, b.y, acc[2][1]);
            acc[2][2] = fmaf(a2, b.z, acc[2][2]); acc[2][3] = fmaf(a2, b.w, acc[2][3]);
            acc[3][0] = fmaf(a3, b.x, acc[3][0]); acc[3][1] = fmaf(a3, b.y, acc[3][1]);
            acc[3][2] = fmaf(a3, b.z, acc[3][2]); acc[3][3] = fmaf(a3, b.w, acc[3][3]);
        }
        __syncthreads();
    }
    float4 bb = *(const float4*)(bout + c0 + tx * 4);
#pragma unroll
    for (int r = 0; r < 4; ++r) {
        *(float4*)(out + (i0 + ty * 4 + r) * C_DIM + c0 + tx * 4) =
            make_float4(acc[r][0] + bb.x, acc[r][1] + bb.y, acc[r][2] + bb.z, acc[r][3] + bb.w);
    }
}

extern "C" void kernel_launch(void* const* d_in, const int* in_sizes, int n_in,
                              void* d_out, int out_size, void* d_ws, size_t ws_size,
                              hipStream_t stream) {
    const float* x     = (const float*)d_in[0];
    const float* rot   = (const float*)d_in[1];
    const float* trans = (const float*)d_in[2];
    const float* Wq    = (const float*)d_in[3];
    const float* Wk    = (const float*)d_in[4];
    const float* Wv    = (const float*)d_in[5];
    const float* Wqp   = (const float*)d_in[6];
    const float* Wkp   = (const float*)d_in[7];
    const float* Wvp   = (const float*)d_in[8];
    const float* Wout  = (const float*)d_in[9];
    const float* bout  = (const float*)d_in[10];
    float* out = (float*)d_out;

    float* ws = (float*)d_ws;
    float* Wall = ws;                             // 384*1024
    float* P    = Wall + C_DIM * PCOLS;           // 1024*1024
    float* KVg  = P    + N_TOK * PCOLS;           // 12*64*1024
    float* Qg   = KVg  + H_NUM * KVG_ROWS * 1024; // 12*29*1024
    float* qcg  = Qg   + H_NUM * 29 * 1024;       // 12*1024
    float* part = ws;                             // alias Wall+P (1.44M >= 1.43M)
    float* att  = Qg;                             // alias Qg (dead after k_attn)

    k_pack<<<384, 256, 0, stream>>>(Wq, Wk, Wv, Wqp, Wkp, Wvp, Wall);
    k_proj<<<dim3(16, 16), 256, 0, stream>>>(x, Wall, P);
    k_prep<<<dim3(8, 12), 256, 0, stream>>>(P, rot, trans, KVg, Qg, qcg);
    k_attn<<<768, 256, 0, stream>>>(KVg, Qg, qcg, part);
    k_comb<<<48, 256, 0, stream>>>(part, rot, trans, att);
    k_out<<<dim3(16, 6), 256, 0, stream>>>(att, Wout, bout, out);
}

// Round 14
// 85.609 us; speedup vs baseline: 1.3353x; 1.3353x over previous
//
#include <hip/hip_runtime.h>
#include <math.h>

#define N_TOK 1024
#define C_DIM 384
#define H_NUM 12
#define PCOLS 1024
#define Q0 0
#define K0 192
#define V0 384
#define QP0 576
#define KP0 720
#define VP0 864
#define ATT_W 240
#define COEF 0.11785113019775792f   // 0.5*sqrt(2/36)
#define ISD 0.25f
#define CC2 (COEF * ISD)            // 0.029462...
#define KV_ROWS 60                  // 29 K' + 28 V' + 3 pad (DMA tiles by 4 rows)
#define NZ 4

// ---------- proj GEMM: direct-W read, transposed A-tile, LDS B, reg-prefetch ----------
// grid (16,16), 256 thr (16 ty x 16 tx). Thread: 4 rows x 4 cols, BK=16.
__global__ __launch_bounds__(256) void k_proj(
    const float* __restrict__ x,
    const float* __restrict__ Wq, const float* __restrict__ Wk, const float* __restrict__ Wv,
    const float* __restrict__ Wqp, const float* __restrict__ Wkp, const float* __restrict__ Wvp,
    float* __restrict__ P)
{
    __shared__ float xs[16][68];    // [k][row], padded
    __shared__ float wsh[16][64];
    int tid = threadIdx.x;
    int i0 = blockIdx.x * 64, c0 = blockIdx.y * 64;
    int lr = tid >> 2, lk = (tid & 3) * 4;
    int wr = tid >> 4, wc = (tid & 15) * 4;
    int ty = tid >> 4, tx = tid & 15;

    // per-thread weight source for column c0+wc (boundaries all multiples of 16)
    int col = c0 + wc;
    const float* Wb; int od, cb;
    if (col < 192)       { Wb = Wq;  od = 192; cb = col; }
    else if (col < 384)  { Wb = Wk;  od = 192; cb = col - 192; }
    else if (col < 576)  { Wb = Wv;  od = 192; cb = col - 384; }
    else if (col < 720)  { Wb = Wqp; od = 144; cb = col - 576; }
    else if (col < 864)  { Wb = Wkp; od = 144; cb = col - 720; }
    else if (col < 1008) { Wb = Wvp; od = 144; cb = col - 864; }
    else                 { Wb = nullptr; od = 0; cb = 0; }

    float4 xa = *(const float4*)(x + (i0 + lr) * C_DIM + lk);
    float4 wa = Wb ? *(const float4*)(Wb + wr * od + cb) : make_float4(0.f, 0.f, 0.f, 0.f);
    float acc[4][4] = {};

    for (int it = 0; it < 24; ++it) {
        xs[lk + 0][lr] = xa.x; xs[lk + 1][lr] = xa.y;
        xs[lk + 2][lr] = xa.z; xs[lk + 3][lr] = xa.w;
        *(float4*)&wsh[wr][wc] = wa;
        __syncthreads();
        if (it < 23) {
            xa = *(const float4*)(x + (i0 + lr) * C_DIM + (it + 1) * 16 + lk);
            wa = Wb ? *(const float4*)(Wb + ((it + 1) * 16 + wr) * od + cb)
                    : make_float4(0.f, 0.f, 0.f, 0.f);
        }
#pragma unroll
        for (int kk = 0; kk < 16; ++kk) {
            float4 a = *(float4*)&xs[kk][ty * 4];
            float4 b = *(float4*)&wsh[kk][tx * 4];
            acc[0][0] = fmaf(a.x, b.x, acc[0][0]); acc[0][1] = fmaf(a.x, b.y, acc[0][1]);
            acc[0][2] = fmaf(a.x, b.z, acc[0][2]); acc[0][3] = fmaf(a.x, b.w, acc[0][3]);
            acc[1][0] = fmaf(a.y, b.x, acc[1][0]); acc[1][1] = fmaf(a.y, b.y, acc[1][1]);
            acc[1][2] = fmaf(a.y, b.z, acc[1][2]); acc[1][3] = fmaf(a.y, b.w, acc[1][3]);
            acc[2][0] = fmaf(a.z, b.x, acc[2][0]); acc[2][1] = fmaf(a.z, b.y, acc[2][1]);
            acc[2][2] = fmaf(a.z, b.z, acc[2][2]); acc[2][3] = fmaf(a.z, b.w, acc[2][3]);
            acc[3][0] = fmaf(a.w, b.x, acc[3][0]); acc[3][1] = fmaf(a.w, b.y, acc[3][1]);
            acc[3][2] = fmaf(a.w, b.z, acc[3][2]); acc[3][3] = fmaf(a.w, b.w, acc[3][3]);
        }
        __syncthreads();
    }
#pragma unroll
    for (int r = 0; r < 4; ++r)
        *(float4*)(P + (i0 + ty * 4 + r) * PCOLS + c0 + tx * 4) =
            make_float4(acc[r][0], acc[r][1], acc[r][2], acc[r][3]);
}

// ---------- prep: build d-major Q'[h][29][1024], KV'[h][60][1024], qc[h][1024] ----------
__global__ __launch_bounds__(256) void k_prep(
    const float* __restrict__ P, const float* __restrict__ rot, const float* __restrict__ trans,
    float* __restrict__ KVg, float* __restrict__ Qg, float* __restrict__ qcg)
{
    __shared__ float kb[29 * 128];
    __shared__ float qb[29 * 128];
    __shared__ float vb[28 * 128];
    __shared__ float qcb[128];
    int h = blockIdx.y, nb = blockIdx.x;
    int tid = threadIdx.x;
    int nl = tid & 127, role = tid >> 7;
    int n = nb * 128 + nl;
    const float* R = rot + n * 9;
    float R00 = R[0], R01 = R[1], R02 = R[2];
    float R10 = R[3], R11 = R[4], R12 = R[5];
    float R20 = R[6], R21 = R[7], R22 = R[8];
    float t0 = trans[n * 3 + 0], t1 = trans[n * 3 + 1], t2 = trans[n * 3 + 2];

    if (role == 0) {
        const float* kr = P + n * PCOLS + K0 + h * 16;
#pragma unroll
        for (int d = 0; d < 16; ++d) kb[d * 128 + nl] = kr[d];
        const float* kp = P + n * PCOLS + KP0 + h * 12;
        float k2 = 0.f;
#pragma unroll
        for (int pt = 0; pt < 4; ++pt) {
            float p0 = kp[pt * 3 + 0], p1 = kp[pt * 3 + 1], p2 = kp[pt * 3 + 2];
            float g0 = R00 * p0 + R01 * p1 + R02 * p2 + t0;
            float g1 = R10 * p0 + R11 * p1 + R12 * p2 + t1;
            float g2 = R20 * p0 + R21 * p1 + R22 * p2 + t2;
            kb[(16 + pt * 3 + 0) * 128 + nl] = g0;
            kb[(16 + pt * 3 + 1) * 128 + nl] = g1;
            kb[(16 + pt * 3 + 2) * 128 + nl] = g2;
            k2 += g0 * g0 + g1 * g1 + g2 * g2;
        }
        kb[28 * 128 + nl] = -CC2 * k2;
    } else {
        const float* qr = P + n * PCOLS + Q0 + h * 16;
#pragma unroll
        for (int d = 0; d < 16; ++d) qb[d * 128 + nl] = qr[d] * ISD;
        const float* qp = P + n * PCOLS + QP0 + h * 12;
        float q2 = 0.f;
#pragma unroll
        for (int pt = 0; pt < 4; ++pt) {
            float p0 = qp[pt * 3 + 0], p1 = qp[pt * 3 + 1], p2 = qp[pt * 3 + 2];
            float g0 = R00 * p0 + R01 * p1 + R02 * p2 + t0;
            float g1 = R10 * p0 + R11 * p1 + R12 * p2 + t1;
            float g2 = R20 * p0 + R21 * p1 + R22 * p2 + t2;
            qb[(16 + pt * 3 + 0) * 128 + nl] = g0 * (2.f * CC2);
            qb[(16 + pt * 3 + 1) * 128 + nl] = g1 * (2.f * CC2);
            qb[(16 + pt * 3 + 2) * 128 + nl] = g2 * (2.f * CC2);
            q2 += g0 * g0 + g1 * g1 + g2 * g2;
        }
        qb[28 * 128 + nl] = 1.0f;
        qcb[nl] = fmaf(-CC2, q2, -4.0f);
        const float* vr = P + n * PCOLS + V0 + h * 16;
#pragma unroll
        for (int d = 0; d < 16; ++d) vb[d * 128 + nl] = vr[d];
        const float* vp = P + n * PCOLS + VP0 + h * 12;
#pragma unroll
        for (int pt = 0; pt < 4; ++pt) {
            float p0 = vp[pt * 3 + 0], p1 = vp[pt * 3 + 1], p2 = vp[pt * 3 + 2];
            vb[(16 + pt * 3 + 0) * 128 + nl] = R00 * p0 + R01 * p1 + R02 * p2 + t0;
            vb[(16 + pt * 3 + 1) * 128 + nl] = R10 * p0 + R11 * p1 + R12 * p2 + t1;
            vb[(16 + pt * 3 + 2) * 128 + nl] = R20 * p0 + R21 * p1 + R22 * p2 + t2;
        }
    }
    __syncthreads();

    for (int u = tid; u < 57 * 32; u += 256) {
        int d = u >> 5, c4 = u & 31;
        float4 v = (d < 29) ? *(float4*)&kb[d * 128 + c4 * 4]
                            : *(float4*)&vb[(d - 29) * 128 + c4 * 4];
        *(float4*)&KVg[(h * KV_ROWS + d) * 1024 + nb * 128 + c4 * 4] = v;
    }
    for (int u = tid; u < 29 * 32; u += 256) {
        int d = u >> 5, c4 = u & 31;
        *(float4*)&Qg[(h * 29 + d) * 1024 + nb * 128 + c4 * 4] = *(float4*)&qb[d * 128 + c4 * 4];
    }
    if (tid < 32) *(float4*)&qcg[h * 1024 + nb * 128 + tid * 4] = *(float4*)&qcb[tid * 4];
}

// ---------- attention: 2q x 8k reg-tiled GEMM, Q' in registers, DMA staging ----------
// 1-D grid 768 with XCD-colocating remap. 256 thr: ty=tid>>3 (32 x 2q), tx=tid&7 (8 x 8k).
__global__ __launch_bounds__(256, 2) void k_attn(
    const float* __restrict__ KVg, const float* __restrict__ Qg,
    const float* __restrict__ qcg, float* __restrict__ part)
{
    __shared__ float KV[2][KV_ROWS * 64];
    __shared__ float red[29 * 64];
    int tid = threadIdx.x;
    int lane = tid & 63, w = tid >> 6;
    int ty = tid >> 3, tx = tid & 7;

    int bid = blockIdx.x;
    int xcd = bid & 7, slot = bid >> 3;
    int pair = xcd * 6 + (slot >> 4);     // 0..47
    int bx = slot & 15;
    int h = pair % H_NUM;
    int z = pair / H_NUM;

    int i0 = bx * 64;
    int jz0 = z * 256;
    const float* KVh = KVg + h * KV_ROWS * 1024;

    // Q' into registers: 2 queries x 29 dims
    float q0[29], q1[29];
#pragma unroll
    for (int d = 0; d < 29; ++d) {
        float2 qv = *(const float2*)&Qg[(h * 29 + d) * 1024 + i0 + ty * 2];
        q0[d] = qv.x; q1[d] = qv.y;
    }
    float qc[2];
    {
        float2 qcv = *(const float2*)&qcg[h * 1024 + i0 + ty * 2];
        qc[0] = qcv.x; qc[1] = qcv.y;
    }

    // wave w issues DMA instr g = w*4+m; each instr stages 1KB = 4 rows of [64].
    int nst = (w < 3) ? 4 : 3;
#define STAGE(T) do { float* buf_ = KV[(T) & 1]; int j0_ = jz0 + (T) * 64;        \
        for (int m_ = 0; m_ < nst; ++m_) {                                        \
            int g_ = w * 4 + m_;                                                  \
            const float* src_ = KVh + (g_ * 4 + (lane >> 4)) * 1024 + j0_ + (lane & 15) * 4; \
            float* dst_ = buf_ + g_ * 256;                                        \
            __builtin_amdgcn_global_load_lds(                                     \
                (const __attribute__((address_space(1))) void*)src_,              \
                (__attribute__((address_space(3))) void*)dst_, 16, 0, 0);         \
        } } while (0)

    STAGE(0);
    __syncthreads();

    float out[2][28] = {};
    float denom[2] = {};

    for (int t = 0; t < 4; ++t) {
        if (t < 3) STAGE(t + 1);
        const float* Kb = KV[t & 1];
        const float* Vb = Kb + 29 * 64;

        float s[2][8] = {};
#pragma unroll
        for (int d = 0; d < 29; ++d) {
            float4 k0 = *(const float4*)&Kb[d * 64 + tx * 8];
            float4 k1 = *(const float4*)&Kb[d * 64 + tx * 8 + 4];
            float ka[8] = {k0.x, k0.y, k0.z, k0.w, k1.x, k1.y, k1.z, k1.w};
#pragma unroll
            for (int j = 0; j < 8; ++j) {
                s[0][j] = fmaf(q0[d], ka[j], s[0][j]);
                s[1][j] = fmaf(q1[d], ka[j], s[1][j]);
            }
        }

        float p[2][8];
#pragma unroll
        for (int r = 0; r < 2; ++r) {
#pragma unroll
            for (int j = 0; j < 8; ++j) {
                p[r][j] = __expf(s[r][j] + qc[r]);
                denom[r] += p[r][j];
            }
        }

#pragma unroll
        for (int d = 0; d < 28; ++d) {
            float4 v0 = *(const float4*)&Vb[d * 64 + tx * 8];
            float4 v1 = *(const float4*)&Vb[d * 64 + tx * 8 + 4];
            float va[8] = {v0.x, v0.y, v0.z, v0.w, v1.x, v1.y, v1.z, v1.w};
#pragma unroll
            for (int r = 0; r < 2; ++r) {
                float acc = out[r][d];
#pragma unroll
                for (int j = 0; j < 8; ++j) acc = fmaf(p[r][j], va[j], acc);
                out[r][d] = acc;
            }
        }
        __syncthreads();
    }

    // butterfly reduce across the 8 tx lanes (lane bits 0..2)
#pragma unroll
    for (int m = 1; m <= 4; m <<= 1) {
#pragma unroll
        for (int r = 0; r < 2; ++r) {
#pragma unroll
            for (int d = 0; d < 28; ++d) out[r][d] += __shfl_xor(out[r][d], m, 64);
            denom[r] += __shfl_xor(denom[r], m, 64);
        }
    }
    if (tx == 0) {
#pragma unroll
        for (int r = 0; r < 2; ++r) {
#pragma unroll
            for (int d = 0; d < 28; ++d) red[d * 64 + ty * 2 + r] = out[r][d];
            red[28 * 64 + ty * 2 + r] = denom[r];
        }
    }
    __syncthreads();
    for (int u = tid; u < 29 * 64; u += 256) {
        part[((z * H_NUM + h) * 29 + (u >> 6)) * N_TOK + i0 + (u & 63)] = red[u];
    }
}

// ---------- combine 4 partials, normalize, point-norm epilogue ----------
__global__ __launch_bounds__(256) void k_comb(
    const float* __restrict__ part, const float* __restrict__ rot,
    const float* __restrict__ trans, float* __restrict__ att)
{
    int t = blockIdx.x * 256 + threadIdx.x;
    int h = t >> 10, i = t & 1023;
    float v[29];
#pragma unroll
    for (int c = 0; c < 29; ++c) {
        float s = 0.f;
#pragma unroll
        for (int z = 0; z < NZ; ++z)
            s += part[((z * H_NUM + h) * 29 + c) * N_TOK + i];
        v[c] = s;
    }
    float inv = 1.f / v[28];
    float* arow = att + i * ATT_W;
#pragma unroll
    for (int d = 0; d < 16; ++d) arow[h * 16 + d] = v[d] * inv;
    float t0 = trans[i * 3 + 0], t1 = trans[i * 3 + 1], t2v = trans[i * 3 + 2];
    const float* R = rot + i * 9;
#pragma unroll
    for (int p = 0; p < 4; ++p) {
        float c0 = v[16 + p * 3 + 0] * inv - t0;
        float c1 = v[16 + p * 3 + 1] * inv - t1;
        float c2 = v[16 + p * 3 + 2] * inv - t2v;
        float l0 = R[0] * c0 + R[3] * c1 + R[6] * c2;
        float l1 = R[1] * c0 + R[4] * c1 + R[7] * c2;
        float l2 = R[2] * c0 + R[5] * c1 + R[8] * c2;
        arow[192 + h * 4 + p] = sqrtf(l0 * l0 + l1 * l1 + l2 * l2);
    }
}

// ---------- out GEMM (r10 classic): LDS-staged, reg-prefetch, grid (16,6) ----------
__global__ __launch_bounds__(256) void k_out(
    const float* __restrict__ att, const float* __restrict__ Wout,
    const float* __restrict__ bout, float* __restrict__ out)
{
    __shared__ float xs[64][17];
    __shared__ float wsh[16][64];
    int tid = threadIdx.x;
    int i0 = blockIdx.x * 64, c0 = blockIdx.y * 64;
    int lr = tid >> 2, lk = (tid & 3) * 4;
    int wr = tid >> 4, wc = (tid & 15) * 4;
    int ty = tid >> 4, tx = tid & 15;

    float4 xa = *(const float4*)(att + (i0 + lr) * ATT_W + lk);
    float4 wa = *(const float4*)(Wout + wr * C_DIM + c0 + wc);
    float acc[4][4] = {};

    for (int it = 0; it < 15; ++it) {
        xs[lr][lk + 0] = xa.x; xs[lr][lk + 1] = xa.y;
        xs[lr][lk + 2] = xa.z; xs[lr][lk + 3] = xa.w;
        *(float4*)&wsh[wr][wc] = wa;
        __syncthreads();
        if (it < 14) {
            xa = *(const float4*)(att + (i0 + lr) * ATT_W + (it + 1) * 16 + lk);
            wa = *(const float4*)(Wout + ((it + 1) * 16 + wr) * C_DIM + c0 + wc);
        }
#pragma unroll
        for (int kk = 0; kk < 16; ++kk) {
            float4 b = *(float4*)&wsh[kk][tx * 4];
            float a0 = xs[ty * 4 + 0][kk];
            float a1 = xs[ty * 4 + 1][kk];
            float a2 = xs[ty * 4 + 2][kk];
            float a3 = xs[ty * 4 + 3][kk];
            acc[0][0] = fmaf(a0, b.x, acc[0][0]); acc[0][1] = fmaf(a0, b.y, acc[0][1]);
            acc[0][2] = fmaf(a0, b.z, acc[0][2]); acc[0][3] = fmaf(a0, b.w, acc[0][3]);
            acc[1][0] = fmaf(a1, b.x, acc[1][0]); acc[1][1] = fmaf(a1, b.y, acc[1][1]);
            acc[1][2] = fmaf(a1, b.z, acc[1][2]); acc[1][3] = fmaf(a1, b.w, acc[1][3]);
            acc[2][0] = fmaf(a2, b.x, acc[2][0]); acc[2][1] = fmaf(a2, b.y, acc[2][1]);
            acc[2][2] = fmaf(a2, b.z, acc[2][2]); acc[2][3] = fmaf(a2, b.w, acc[2][3]);
            acc[3][0] = fmaf(a3, b.x, acc[3][0]); acc[3][1] = fmaf(a3, b.y, acc[3][1]);
            acc[3][2] = fmaf(a3, b.z, acc[3][2]); acc[3][3] = fmaf(a3, b.w, acc[3][3]);
        }
        __syncthreads();
    }
    float4 bb = *(const float4*)(bout + c0 + tx * 4);
#pragma unroll
    for (int r = 0; r < 4; ++r) {
        *(float4*)(out + (i0 + ty * 4 + r) * C_DIM + c0 + tx * 4) =
            make_float4(acc[r][0] + bb.x, acc[r][1] + bb.y, acc[r][2] + bb.z, acc[r][3] + bb.w);
    }
}

extern "C" void kernel_launch(void* const* d_in, const int* in_sizes, int n_in,
                              void* d_out, int out_size, void* d_ws, size_t ws_size,
                              hipStream_t stream) {
    const float* x     = (const float*)d_in[0];
    const float* rot   = (const float*)d_in[1];
    const float* trans = (const float*)d_in[2];
    const float* Wq    = (const float*)d_in[3];
    const float* Wk    = (const float*)d_in[4];
    const float* Wv    = (const float*)d_in[5];
    const float* Wqp   = (const float*)d_in[6];
    const float* Wkp   = (const float*)d_in[7];
    const float* Wvp   = (const float*)d_in[8];
    const float* Wout  = (const float*)d_in[9];
    const float* bout  = (const float*)d_in[10];
    float* out = (float*)d_out;

    float* ws  = (float*)d_ws;
    float* P    = ws;                              // 1024*1024
    float* KVg  = P    + N_TOK * PCOLS;            // 12*60*1024
    float* Qg   = KVg  + H_NUM * KV_ROWS * 1024;   // 12*29*1024
    float* qcg  = Qg   + H_NUM * 29 * 1024;        // 12*1024
    float* part = qcg  + H_NUM * 1024;             // 4*12*29*1024
    float* att  = part + NZ * H_NUM * 29 * 1024;   // 1024*240

    k_proj<<<dim3(16, 16), 256, 0, stream>>>(x, Wq, Wk, Wv, Wqp, Wkp, Wvp, P);
    k_prep<<<dim3(8, 12), 256, 0, stream>>>(P, rot, trans, KVg, Qg, qcg);
    k_attn<<<768, 256, 0, stream>>>(KVg, Qg, qcg, part);
    k_comb<<<48, 256, 0, stream>>>(part, rot, trans, att);
    k_out<<<dim3(16, 6), 256, 0, stream>>>(att, Wout, bout, out);
}

// Round 17
// 84.439 us; speedup vs baseline: 1.3538x; 1.0139x over previous
//
#include <hip/hip_runtime.h>
#include <math.h>

#define N_TOK 1024
#define C_DIM 384
#define H_NUM 12
#define PCOLS 1024
#define Q0 0
#define K0 192
#define V0 384
#define QP0 576
#define KP0 720
#define VP0 864
#define ATT_W 240
#define COEF 0.11785113019775792f   // 0.5*sqrt(2/36)
#define ISD 0.25f
#define CC2 (COEF * ISD)            // 0.029462...
#define NZ 4
// packed KV tile (u32 units):
//   [0,896)      K' fp16 pairs   [14 dp][64 j]
//   [896,1408)   V scalar fp16   [16 d][32 jp]
//   [1408,2176)  V point f32     [12 d][64 j]
//   [2176,2240)  k2 f32          [64 j]
#define OKV_V16 896
#define OKV_VP 1408
#define OKV_K2 2176
#define TILE_U 2240
#define TILE_PAD 2304               // 9 KB per (h, 64-key tile): 9 x 1KB DMA

typedef _Float16 f16x2 __attribute__((ext_vector_type(2)));   // fdot2 operand type
typedef __fp16   p16x2 __attribute__((ext_vector_type(2)));   // cvt_pkrtz return type
union U32H2 { unsigned int u; f16x2 f; p16x2 p; };
__device__ __forceinline__ f16x2 as_h2(unsigned int v) { U32H2 x; x.u = v; return x.f; }
__device__ __forceinline__ unsigned int pkh(float a, float b) {
    U32H2 x; x.p = __builtin_amdgcn_cvt_pkrtz(a, b); return x.u;
}
__device__ __forceinline__ f16x2 pkf(float a, float b) {
    U32H2 x; x.p = __builtin_amdgcn_cvt_pkrtz(a, b); return x.f;
}

// ---------- proj GEMM: direct-W read, transposed A-tile, LDS B, reg-prefetch ----------
__global__ __launch_bounds__(256) void k_proj(
    const float* __restrict__ x,
    const float* __restrict__ Wq, const float* __restrict__ Wk, const float* __restrict__ Wv,
    const float* __restrict__ Wqp, const float* __restrict__ Wkp, const float* __restrict__ Wvp,
    float* __restrict__ P)
{
    __shared__ float xs[16][68];
    __shared__ float wsh[16][64];
    int tid = threadIdx.x;
    int i0 = blockIdx.x * 64, c0 = blockIdx.y * 64;
    int lr = tid >> 2, lk = (tid & 3) * 4;
    int wr = tid >> 4, wc = (tid & 15) * 4;
    int ty = tid >> 4, tx = tid & 15;

    int col = c0 + wc;
    const float* Wb; int od, cb;
    if (col < 192)       { Wb = Wq;  od = 192; cb = col; }
    else if (col < 384)  { Wb = Wk;  od = 192; cb = col - 192; }
    else if (col < 576)  { Wb = Wv;  od = 192; cb = col - 384; }
    else if (col < 720)  { Wb = Wqp; od = 144; cb = col - 576; }
    else if (col < 864)  { Wb = Wkp; od = 144; cb = col - 720; }
    else if (col < 1008) { Wb = Wvp; od = 144; cb = col - 864; }
    else                 { Wb = nullptr; od = 0; cb = 0; }

    float4 xa = *(const float4*)(x + (i0 + lr) * C_DIM + lk);
    float4 wa = Wb ? *(const float4*)(Wb + wr * od + cb) : make_float4(0.f, 0.f, 0.f, 0.f);
    float acc[4][4] = {};

    for (int it = 0; it < 24; ++it) {
        xs[lk + 0][lr] = xa.x; xs[lk + 1][lr] = xa.y;
        xs[lk + 2][lr] = xa.z; xs[lk + 3][lr] = xa.w;
        *(float4*)&wsh[wr][wc] = wa;
        __syncthreads();
        if (it < 23) {
            xa = *(const float4*)(x + (i0 + lr) * C_DIM + (it + 1) * 16 + lk);
            wa = Wb ? *(const float4*)(Wb + ((it + 1) * 16 + wr) * od + cb)
                    : make_float4(0.f, 0.f, 0.f, 0.f);
        }
#pragma unroll
        for (int kk = 0; kk < 16; ++kk) {
            float4 a = *(float4*)&xs[kk][ty * 4];
            float4 b = *(float4*)&wsh[kk][tx * 4];
            acc[0][0] = fmaf(a.x, b.x, acc[0][0]); acc[0][1] = fmaf(a.x, b.y, acc[0][1]);
            acc[0][2] = fmaf(a.x, b.z, acc[0][2]); acc[0][3] = fmaf(a.x, b.w, acc[0][3]);
            acc[1][0] = fmaf(a.y, b.x, acc[1][0]); acc[1][1] = fmaf(a.y, b.y, acc[1][1]);
            acc[1][2] = fmaf(a.y, b.z, acc[1][2]); acc[1][3] = fmaf(a.y, b.w, acc[1][3]);
            acc[2][0] = fmaf(a.z, b.x, acc[2][0]); acc[2][1] = fmaf(a.z, b.y, acc[2][1]);
            acc[2][2] = fmaf(a.z, b.z, acc[2][2]); acc[2][3] = fmaf(a.z, b.w, acc[2][3]);
            acc[3][0] = fmaf(a.w, b.x, acc[3][0]); acc[3][1] = fmaf(a.w, b.y, acc[3][1]);
            acc[3][2] = fmaf(a.w, b.z, acc[3][2]); acc[3][3] = fmaf(a.w, b.w, acc[3][3]);
        }
        __syncthreads();
    }
#pragma unroll
    for (int r = 0; r < 4; ++r)
        *(float4*)(P + (i0 + ty * 4 + r) * PCOLS + c0 + tx * 4) =
            make_float4(acc[r][0], acc[r][1], acc[r][2], acc[r][3]);
}

// ---------- prep: mixed-precision packed KV tiles + fp16 Q' pairs + f32 qc ----------
// grid (8 nb, 12 h), 256 thr. Each block: 128 tokens = 2 key-tiles.
__global__ __launch_bounds__(256) void k_prep(
    const float* __restrict__ P, const float* __restrict__ rot, const float* __restrict__ trans,
    unsigned int* __restrict__ KVT, unsigned int* __restrict__ Qh, float* __restrict__ qcg)
{
    __shared__ float kb[29 * 128];   // rows 0..27 K' dims, row 28 = -CC2*k2 (f32)
    __shared__ float qb[28 * 128];   // Q' dims (scaled)
    __shared__ float vb[28 * 128];   // rows 0..15 V scalar, 16..27 V point
    __shared__ float qcb[128];
    int h = blockIdx.y, nb = blockIdx.x;
    int tid = threadIdx.x;
    int nl = tid & 127, role = tid >> 7;
    int n = nb * 128 + nl;
    const float* R = rot + n * 9;
    float R00 = R[0], R01 = R[1], R02 = R[2];
    float R10 = R[3], R11 = R[4], R12 = R[5];
    float R20 = R[6], R21 = R[7], R22 = R[8];
    float t0 = trans[n * 3 + 0], t1 = trans[n * 3 + 1], t2 = trans[n * 3 + 2];

    if (role == 0) {
        const float* kr = P + n * PCOLS + K0 + h * 16;
#pragma unroll
        for (int d = 0; d < 16; ++d) kb[d * 128 + nl] = kr[d];
        const float* kp = P + n * PCOLS + KP0 + h * 12;
        float k2 = 0.f;
#pragma unroll
        for (int pt = 0; pt < 4; ++pt) {
            float p0 = kp[pt * 3 + 0], p1 = kp[pt * 3 + 1], p2 = kp[pt * 3 + 2];
            float g0 = R00 * p0 + R01 * p1 + R02 * p2 + t0;
            float g1 = R10 * p0 + R11 * p1 + R12 * p2 + t1;
            float g2 = R20 * p0 + R21 * p1 + R22 * p2 + t2;
            kb[(16 + pt * 3 + 0) * 128 + nl] = g0;
            kb[(16 + pt * 3 + 1) * 128 + nl] = g1;
            kb[(16 + pt * 3 + 2) * 128 + nl] = g2;
            k2 += g0 * g0 + g1 * g1 + g2 * g2;
        }
        kb[28 * 128 + nl] = -CC2 * k2;
    } else {
        const float* qr = P + n * PCOLS + Q0 + h * 16;
#pragma unroll
        for (int d = 0; d < 16; ++d) qb[d * 128 + nl] = qr[d] * ISD;
        const float* qp = P + n * PCOLS + QP0 + h * 12;
        float q2 = 0.f;
#pragma unroll
        for (int pt = 0; pt < 4; ++pt) {
            float p0 = qp[pt * 3 + 0], p1 = qp[pt * 3 + 1], p2 = qp[pt * 3 + 2];
            float g0 = R00 * p0 + R01 * p1 + R02 * p2 + t0;
            float g1 = R10 * p0 + R11 * p1 + R12 * p2 + t1;
            float g2 = R20 * p0 + R21 * p1 + R22 * p2 + t2;
            qb[(16 + pt * 3 + 0) * 128 + nl] = g0 * (2.f * CC2);
            qb[(16 + pt * 3 + 1) * 128 + nl] = g1 * (2.f * CC2);
            qb[(16 + pt * 3 + 2) * 128 + nl] = g2 * (2.f * CC2);
            q2 += g0 * g0 + g1 * g1 + g2 * g2;
        }
        qcb[nl] = fmaf(-CC2, q2, -4.0f);
        const float* vr = P + n * PCOLS + V0 + h * 16;
#pragma unroll
        for (int d = 0; d < 16; ++d) vb[d * 128 + nl] = vr[d];
        const float* vp = P + n * PCOLS + VP0 + h * 12;
#pragma unroll
        for (int pt = 0; pt < 4; ++pt) {
            float p0 = vp[pt * 3 + 0], p1 = vp[pt * 3 + 1], p2 = vp[pt * 3 + 2];
            vb[(16 + pt * 3 + 0) * 128 + nl] = R00 * p0 + R01 * p1 + R02 * p2 + t0;
            vb[(16 + pt * 3 + 1) * 128 + nl] = R10 * p0 + R11 * p1 + R12 * p2 + t1;
            vb[(16 + pt * 3 + 2) * 128 + nl] = R20 * p0 + R21 * p1 + R22 * p2 + t2;
        }
    }
    __syncthreads();

    // write 2 packed tiles
    for (int u = tid; u < 2 * TILE_PAD; u += 256) {
        int tt = u / TILE_PAD, r = u % TILE_PAD;
        unsigned int val;
        if (r < OKV_V16) {
            int dp = r >> 6, j = r & 63;
            val = pkh(kb[(2 * dp) * 128 + tt * 64 + j], kb[(2 * dp + 1) * 128 + tt * 64 + j]);
        } else if (r < OKV_VP) {
            int idx = r - OKV_V16;
            int d = idx >> 5, jp = idx & 31;
            val = pkh(vb[d * 128 + tt * 64 + 2 * jp], vb[d * 128 + tt * 64 + 2 * jp + 1]);
        } else if (r < OKV_K2) {
            int idx = r - OKV_VP;
            int d = idx >> 6, j = idx & 63;
            val = __float_as_uint(vb[(16 + d) * 128 + tt * 64 + j]);
        } else if (r < TILE_U) {
            int j = r - OKV_K2;
            val = __float_as_uint(kb[28 * 128 + tt * 64 + j]);
        } else {
            val = 0u;
        }
        KVT[(h * 16 + nb * 2 + tt) * TILE_PAD + r] = val;
    }
    // Q' pairs
    for (int u = tid; u < 14 * 128; u += 256) {
        int dp = u >> 7, n2 = u & 127;
        Qh[(h * 14 + dp) * 1024 + nb * 128 + n2] =
            pkh(qb[(2 * dp) * 128 + n2], qb[(2 * dp + 1) * 128 + n2]);
    }
    if (tid < 32) *(float4*)&qcg[h * 1024 + nb * 128 + tid * 4] = *(float4*)&qcb[tid * 4];
}

// ---------- attention: fp16 logits + mixed PV, 2q x 8k, DMA staging ----------
// 1-D grid 768, XCD-colocating remap. 256 thr: ty=tid>>3 (32 x 2q), tx=tid&7 (8 x 8k).
__global__ __launch_bounds__(256, 2) void k_attn(
    const unsigned int* __restrict__ KVT, const unsigned int* __restrict__ Qh,
    const float* __restrict__ qcg, float* __restrict__ part)
{
    __shared__ unsigned int KV[2][TILE_PAD];
    __shared__ float red[29 * 64];
    int tid = threadIdx.x;
    int lane = tid & 63, w = tid >> 6;
    int ty = tid >> 3, tx = tid & 7;

    int bid = blockIdx.x;
    int xcd = bid & 7, slot = bid >> 3;
    int pair = xcd * 6 + (slot >> 4);
    int bx = slot & 15;
    int h = pair % H_NUM;
    int z = pair / H_NUM;

    int i0 = bx * 64;
    const unsigned int* KVbase = KVT + (h * 16 + z * 4) * TILE_PAD;

    // Q' pairs into registers (2 queries x 14 dp)
    f16x2 q0p[14], q1p[14];
#pragma unroll
    for (int dp = 0; dp < 14; ++dp) {
        q0p[dp] = as_h2(Qh[(h * 14 + dp) * 1024 + i0 + ty * 2 + 0]);
        q1p[dp] = as_h2(Qh[(h * 14 + dp) * 1024 + i0 + ty * 2 + 1]);
    }
    float qc[2];
    {
        float2 qcv = *(const float2*)&qcg[h * 1024 + i0 + ty * 2];
        qc[0] = qcv.x; qc[1] = qcv.y;
    }

    // 9 x 1KB DMA per tile; waves issue {3,2,2,2}
    int nst = (w == 0) ? 3 : 2;
    int gbase = (w == 0) ? 0 : 1 + w * 2;
#define STAGE(T) do { unsigned int* buf_ = KV[(T) & 1];                          \
        const unsigned int* sb_ = KVbase + (T) * TILE_PAD;                       \
        for (int m_ = 0; m_ < nst; ++m_) {                                       \
            int g_ = gbase + m_;                                                 \
            const unsigned int* src_ = sb_ + g_ * 256 + lane * 4;                \
            unsigned int* dst_ = buf_ + g_ * 256;                                \
            __builtin_amdgcn_global_load_lds(                                    \
                (const __attribute__((address_space(1))) void*)src_,             \
                (__attribute__((address_space(3))) void*)dst_, 16, 0, 0);        \
        } } while (0)

    STAGE(0);
    __syncthreads();

    float out[2][28] = {};
    float denom[2] = {};

    for (int t = 0; t < 4; ++t) {
        if (t < 3) STAGE(t + 1);
        const unsigned int* Kb = KV[t & 1];

        float s[2][8] = {};
#pragma unroll
        for (int dp = 0; dp < 14; ++dp) {
            uint4 a = *(const uint4*)&Kb[dp * 64 + tx * 8];
            uint4 b = *(const uint4*)&Kb[dp * 64 + tx * 8 + 4];
            unsigned int ka[8] = {a.x, a.y, a.z, a.w, b.x, b.y, b.z, b.w};
#pragma unroll
            for (int j = 0; j < 8; ++j) {
                s[0][j] = __builtin_amdgcn_fdot2(q0p[dp], as_h2(ka[j]), s[0][j], false);
                s[1][j] = __builtin_amdgcn_fdot2(q1p[dp], as_h2(ka[j]), s[1][j], false);
            }
        }
        const float* k2p = (const float*)&Kb[OKV_K2];
        float4 c0 = *(const float4*)&k2p[tx * 8];
        float4 c1 = *(const float4*)&k2p[tx * 8 + 4];
        float k2v[8] = {c0.x, c0.y, c0.z, c0.w, c1.x, c1.y, c1.z, c1.w};

        float p[2][8];
#pragma unroll
        for (int r = 0; r < 2; ++r) {
#pragma unroll
            for (int j = 0; j < 8; ++j) {
                p[r][j] = __expf(s[r][j] + k2v[j] + qc[r]);
                denom[r] += p[r][j];
            }
        }
        f16x2 pp[2][4];
#pragma unroll
        for (int r = 0; r < 2; ++r)
#pragma unroll
            for (int jp = 0; jp < 4; ++jp)
                pp[r][jp] = pkf(p[r][2 * jp], p[r][2 * jp + 1]);

        // V scalar (fp16 dot2), dims 0..15
#pragma unroll
        for (int d = 0; d < 16; ++d) {
            uint4 vv = *(const uint4*)&Kb[OKV_V16 + d * 32 + tx * 4];
#pragma unroll
            for (int r = 0; r < 2; ++r) {
                float acc = out[r][d];
                acc = __builtin_amdgcn_fdot2(pp[r][0], as_h2(vv.x), acc, false);
                acc = __builtin_amdgcn_fdot2(pp[r][1], as_h2(vv.y), acc, false);
                acc = __builtin_amdgcn_fdot2(pp[r][2], as_h2(vv.z), acc, false);
                acc = __builtin_amdgcn_fdot2(pp[r][3], as_h2(vv.w), acc, false);
                out[r][d] = acc;
            }
        }
        // V point (f32 fma), dims 16..27
#pragma unroll
        for (int d = 0; d < 12; ++d) {
            const float* vp = (const float*)&Kb[OKV_VP + d * 64];
            float4 v0 = *(const float4*)&vp[tx * 8];
            float4 v1 = *(const float4*)&vp[tx * 8 + 4];
            float va[8] = {v0.x, v0.y, v0.z, v0.w, v1.x, v1.y, v1.z, v1.w};
#pragma unroll
            for (int r = 0; r < 2; ++r) {
                float acc = out[r][16 + d];
#pragma unroll
                for (int j = 0; j < 8; ++j) acc = fmaf(p[r][j], va[j], acc);
                out[r][16 + d] = acc;
            }
        }
        __syncthreads();
    }

    // butterfly reduce across the 8 tx lanes
#pragma unroll
    for (int m = 1; m <= 4; m <<= 1) {
#pragma unroll
        for (int r = 0; r < 2; ++r) {
#pragma unroll
            for (int d = 0; d < 28; ++d) out[r][d] += __shfl_xor(out[r][d], m, 64);
            denom[r] += __shfl_xor(denom[r], m, 64);
        }
    }
    if (tx == 0) {
#pragma unroll
        for (int r = 0; r < 2; ++r) {
#pragma unroll
            for (int d = 0; d < 28; ++d) red[d * 64 + ty * 2 + r] = out[r][d];
            red[28 * 64 + ty * 2 + r] = denom[r];
        }
    }
    __syncthreads();
    for (int u = tid; u < 29 * 64; u += 256) {
        part[((z * H_NUM + h) * 29 + (u >> 6)) * N_TOK + i0 + (u & 63)] = red[u];
    }
}

// ---------- combine 4 partials, normalize, point-norm epilogue ----------
__global__ __launch_bounds__(256) void k_comb(
    const float* __restrict__ part, const float* __restrict__ rot,
    const float* __restrict__ trans, float* __restrict__ att)
{
    int t = blockIdx.x * 256 + threadIdx.x;
    int h = t >> 10, i = t & 1023;
    float v[29];
#pragma unroll
    for (int c = 0; c < 29; ++c) {
        float s = 0.f;
#pragma unroll
        for (int z = 0; z < NZ; ++z)
            s += part[((z * H_NUM + h) * 29 + c) * N_TOK + i];
        v[c] = s;
    }
    float inv = 1.f / v[28];
    float* arow = att + i * ATT_W;
#pragma unroll
    for (int d = 0; d < 16; ++d) arow[h * 16 + d] = v[d] * inv;
    float t0 = trans[i * 3 + 0], t1 = trans[i * 3 + 1], t2v = trans[i * 3 + 2];
    const float* R = rot + i * 9;
#pragma unroll
    for (int p = 0; p < 4; ++p) {
        float c0 = v[16 + p * 3 + 0] * inv - t0;
        float c1 = v[16 + p * 3 + 1] * inv - t1;
        float c2 = v[16 + p * 3 + 2] * inv - t2v;
        float l0 = R[0] * c0 + R[3] * c1 + R[6] * c2;
        float l1 = R[1] * c0 + R[4] * c1 + R[7] * c2;
        float l2 = R[2] * c0 + R[5] * c1 + R[8] * c2;
        arow[192 + h * 4 + p] = sqrtf(l0 * l0 + l1 * l1 + l2 * l2);
    }
}

// ---------- out GEMM: LDS-staged, reg-prefetch ----------
__global__ __launch_bounds__(256) void k_out(
    const float* __restrict__ att, const float* __restrict__ Wout,
    const float* __restrict__ bout, float* __restrict__ out)
{
    __shared__ float xs[64][17];
    __shared__ float wsh[16][64];
    int tid = threadIdx.x;
    int i0 = blockIdx.x * 64, c0 = blockIdx.y * 64;
    int lr = tid >> 2, lk = (tid & 3) * 4;
    int wr = tid >> 4, wc = (tid & 15) * 4;
    int ty = tid >> 4, tx = tid & 15;

    float4 xa = *(const float4*)(att + (i0 + lr) * ATT_W + lk);
    float4 wa = *(const float4*)(Wout + wr * C_DIM + c0 + wc);
    float acc[4][4] = {};

    for (int it = 0; it < 15; ++it) {
        xs[lr][lk + 0] = xa.x; xs[lr][lk + 1] = xa.y;
        xs[lr][lk + 2] = xa.z; xs[lr][lk + 3] = xa.w;
        *(float4*)&wsh[wr][wc] = wa;
        __syncthreads();
        if (it < 14) {
            xa = *(const float4*)(att + (i0 + lr) * ATT_W + (it + 1) * 16 + lk);
            wa = *(const float4*)(Wout + ((it + 1) * 16 + wr) * C_DIM + c0 + wc);
        }
#pragma unroll
        for (int kk = 0; kk < 16; ++kk) {
            float4 b = *(float4*)&wsh[kk][tx * 4];
            float a0 = xs[ty * 4 + 0][kk];
            float a1 = xs[ty * 4 + 1][kk];
            float a2 = xs[ty * 4 + 2][kk];
            float a3 = xs[ty * 4 + 3][kk];
            acc[0][0] = fmaf(a0, b.x, acc[0][0]); acc[0][1] = fmaf(a0, b.y, acc[0][1]);
            acc[0][2] = fmaf(a0, b.z, acc[0][2]); acc[0][3] = fmaf(a0, b.w, acc[0][3]);
            acc[1][0] = fmaf(a1, b.x, acc[1][0]); acc[1][1] = fmaf(a1, b.y, acc[1][1]);
            acc[1][2] = fmaf(a1, b.z, acc[1][2]); acc[1][3] = fmaf(a1, b.w, acc[1][3]);
            acc[2][0] = fmaf(a2, b.x, acc[2][0]); acc[2][1] = fmaf(a2, b.y, acc[2][1]);
            acc[2][2] = fmaf(a2, b.z, acc[2][2]); acc[2][3] = fmaf(a2, b.w, acc[2][3]);
            acc[3][0] = fmaf(a3, b.x, acc[3][0]); acc[3][1] = fmaf(a3, b.y, acc[3][1]);
            acc[3][2] = fmaf(a3, b.z, acc[3][2]); acc[3][3] = fmaf(a3, b.w, acc[3][3]);
        }
        __syncthreads();
    }
    float4 bb = *(const float4*)(bout + c0 + tx * 4);
#pragma unroll
    for (int r = 0; r < 4; ++r) {
        *(float4*)(out + (i0 + ty * 4 + r) * C_DIM + c0 + tx * 4) =
            make_float4(acc[r][0] + bb.x, acc[r][1] + bb.y, acc[r][2] + bb.z, acc[r][3] + bb.w);
    }
}

extern "C" void kernel_launch(void* const* d_in, const int* in_sizes, int n_in,
                              void* d_out, int out_size, void* d_ws, size_t ws_size,
                              hipStream_t stream) {
    const float* x     = (const float*)d_in[0];
    const float* rot   = (const float*)d_in[1];
    const float* trans = (const float*)d_in[2];
    const float* Wq    = (const float*)d_in[3];
    const float* Wk    = (const float*)d_in[4];
    const float* Wv    = (const float*)d_in[5];
    const float* Wqp   = (const float*)d_in[6];
    const float* Wkp   = (const float*)d_in[7];
    const float* Wvp   = (const float*)d_in[8];
    const float* Wout  = (const float*)d_in[9];
    const float* bout  = (const float*)d_in[10];
    float* out = (float*)d_out;

    float* ws = (float*)d_ws;
    float* P            = ws;                                 // 1024*1024
    unsigned int* KVT   = (unsigned int*)(P + N_TOK * PCOLS); // 12*16*2304 u32
    unsigned int* Qh    = KVT + H_NUM * 16 * TILE_PAD;        // 12*14*1024 u32
    float* qcg          = (float*)(Qh + H_NUM * 14 * 1024);   // 12*1024
    float* part         = qcg + H_NUM * 1024;                 // 4*12*29*1024
    float* att          = part + NZ * H_NUM * 29 * 1024;      // 1024*240

    k_proj<<<dim3(16, 16), 256, 0, stream>>>(x, Wq, Wk, Wv, Wqp, Wkp, Wvp, P);
    k_prep<<<dim3(8, 12), 256, 0, stream>>>(P, rot, trans, KVT, Qh, qcg);
    k_attn<<<768, 256, 0, stream>>>(KVT, Qh, qcg, part);
    k_comb<<<48, 256, 0, stream>>>(part, rot, trans, att);
    k_out<<<dim3(16, 6), 256, 0, stream>>>(att, Wout, bout, out);
}

// Round 18
// 81.152 us; speedup vs baseline: 1.4086x; 1.0405x over previous
//
#include <hip/hip_runtime.h>
#include <math.h>

#define N_TOK 1024
#define C_DIM 384
#define H_NUM 12
#define PCOLS 1024
#define Q0 0
#define K0 192
#define V0 384
#define QP0 576
#define KP0 720
#define VP0 864
#define ATT_W 240
#define COEF 0.11785113019775792f   // 0.5*sqrt(2/36)
#define ISD 0.25f
#define CC2 (COEF * ISD)            // 0.029462...
#define NZ 4
// packed KV tile (u32 units):
//   [0,896)      K' fp16 pairs   [14 dp][64 j]
//   [896,1408)   V scalar fp16   [16 d][32 jp]
//   [1408,2176)  V point f32     [12 d][64 j]
//   [2176,2240)  k2 f32          [64 j]
#define OKV_V16 896
#define OKV_VP 1408
#define OKV_K2 2176
#define TILE_U 2240
#define TILE_PAD 2304               // 9 KB per (h, 64-key tile): 9 x 1KB DMA

typedef _Float16 f16x2 __attribute__((ext_vector_type(2)));   // fdot2 operand type
typedef __fp16   p16x2 __attribute__((ext_vector_type(2)));   // cvt_pkrtz return type
union U32H2 { unsigned int u; f16x2 f; p16x2 p; };
__device__ __forceinline__ f16x2 as_h2(unsigned int v) { U32H2 x; x.u = v; return x.f; }
__device__ __forceinline__ unsigned int pkh(float a, float b) {
    U32H2 x; x.p = __builtin_amdgcn_cvt_pkrtz(a, b); return x.u;
}
__device__ __forceinline__ f16x2 pkf(float a, float b) {
    U32H2 x; x.p = __builtin_amdgcn_cvt_pkrtz(a, b); return x.f;
}

// ---------- proj GEMM: fp16 operands in LDS, fdot2 inner loop ----------
// grid (16,16), 512 thr (8 waves). Tile 64x64, BK=16 (8 fp16-pairs); thread: 2 rows x 4 cols.
__global__ __launch_bounds__(512) void k_proj(
    const float* __restrict__ x,
    const float* __restrict__ Wq, const float* __restrict__ Wk, const float* __restrict__ Wv,
    const float* __restrict__ Wqp, const float* __restrict__ Wkp, const float* __restrict__ Wvp,
    float* __restrict__ P)
{
    __shared__ unsigned int xs[8][72];    // [dp][row] x k-pairs
    __shared__ unsigned int wsh[8][64];   // [dp][col] W k-pairs
    int tid = threadIdx.x;
    int i0 = blockIdx.x * 64, c0 = blockIdx.y * 64;
    int sdp = tid & 7, slr = tid >> 3;    // x staging: [8 dp][64 rows]
    int wdp = tid >> 6, wcc = tid & 63;   // W staging: [8 dp][64 cols]
    int ty = tid >> 4, tx = tid & 15;     // compute: rows ty*2..+1, cols tx*4..+3

    int col = c0 + wcc;
    const float* Wb; int od, cb;
    if (col < 192)       { Wb = Wq;  od = 192; cb = col; }
    else if (col < 384)  { Wb = Wk;  od = 192; cb = col - 192; }
    else if (col < 576)  { Wb = Wv;  od = 192; cb = col - 384; }
    else if (col < 720)  { Wb = Wqp; od = 144; cb = col - 576; }
    else if (col < 864)  { Wb = Wkp; od = 144; cb = col - 720; }
    else if (col < 1008) { Wb = Wvp; od = 144; cb = col - 864; }
    else                 { Wb = nullptr; od = 0; cb = 0; }

    const float* xr = x + (i0 + slr) * C_DIM;

    float2 xa = *(const float2*)(xr + sdp * 2);
    float w0 = Wb ? Wb[(2 * wdp) * od + cb] : 0.f;
    float w1 = Wb ? Wb[(2 * wdp + 1) * od + cb] : 0.f;
    float acc[2][4] = {};

    for (int it = 0; it < 24; ++it) {
        xs[sdp][slr] = pkh(xa.x, xa.y);
        wsh[wdp][wcc] = pkh(w0, w1);
        __syncthreads();
        if (it < 23) {
            xa = *(const float2*)(xr + (it + 1) * 16 + sdp * 2);
            w0 = Wb ? Wb[((it + 1) * 16 + 2 * wdp) * od + cb] : 0.f;
            w1 = Wb ? Wb[((it + 1) * 16 + 2 * wdp + 1) * od + cb] : 0.f;
        }
#pragma unroll
        for (int dp = 0; dp < 8; ++dp) {
            uint2 au = *(const uint2*)&xs[dp][ty * 2];
            uint4 bu = *(const uint4*)&wsh[dp][tx * 4];
            unsigned int aa[2] = {au.x, au.y};
            unsigned int bb[4] = {bu.x, bu.y, bu.z, bu.w};
#pragma unroll
            for (int r = 0; r < 2; ++r)
#pragma unroll
                for (int c = 0; c < 4; ++c)
                    acc[r][c] = __builtin_amdgcn_fdot2(as_h2(aa[r]), as_h2(bb[c]), acc[r][c], false);
        }
        __syncthreads();
    }
#pragma unroll
    for (int r = 0; r < 2; ++r)
        *(float4*)(P + (i0 + ty * 2 + r) * PCOLS + c0 + tx * 4) =
            make_float4(acc[r][0], acc[r][1], acc[r][2], acc[r][3]);
}

// ---------- prep: mixed-precision packed KV tiles + fp16 Q' pairs + f32 qc ----------
// grid (8 nb, 12 h), 256 thr. Each block: 128 tokens = 2 key-tiles.
__global__ __launch_bounds__(256) void k_prep(
    const float* __restrict__ P, const float* __restrict__ rot, const float* __restrict__ trans,
    unsigned int* __restrict__ KVT, unsigned int* __restrict__ Qh, float* __restrict__ qcg)
{
    __shared__ float kb[29 * 128];   // rows 0..27 K' dims, row 28 = -CC2*k2 (f32)
    __shared__ float qb[28 * 128];   // Q' dims (scaled)
    __shared__ float vb[28 * 128];   // rows 0..15 V scalar, 16..27 V point
    __shared__ float qcb[128];
    int h = blockIdx.y, nb = blockIdx.x;
    int tid = threadIdx.x;
    int nl = tid & 127, role = tid >> 7;
    int n = nb * 128 + nl;
    const float* R = rot + n * 9;
    float R00 = R[0], R01 = R[1], R02 = R[2];
    float R10 = R[3], R11 = R[4], R12 = R[5];
    float R20 = R[6], R21 = R[7], R22 = R[8];
    float t0 = trans[n * 3 + 0], t1 = trans[n * 3 + 1], t2 = trans[n * 3 + 2];

    if (role == 0) {
        const float* kr = P + n * PCOLS + K0 + h * 16;
#pragma unroll
        for (int d = 0; d < 16; ++d) kb[d * 128 + nl] = kr[d];
        const float* kp = P + n * PCOLS + KP0 + h * 12;
        float k2 = 0.f;
#pragma unroll
        for (int pt = 0; pt < 4; ++pt) {
            float p0 = kp[pt * 3 + 0], p1 = kp[pt * 3 + 1], p2 = kp[pt * 3 + 2];
            float g0 = R00 * p0 + R01 * p1 + R02 * p2 + t0;
            float g1 = R10 * p0 + R11 * p1 + R12 * p2 + t1;
            float g2 = R20 * p0 + R21 * p1 + R22 * p2 + t2;
            kb[(16 + pt * 3 + 0) * 128 + nl] = g0;
            kb[(16 + pt * 3 + 1) * 128 + nl] = g1;
            kb[(16 + pt * 3 + 2) * 128 + nl] = g2;
            k2 += g0 * g0 + g1 * g1 + g2 * g2;
        }
        kb[28 * 128 + nl] = -CC2 * k2;
    } else {
        const float* qr = P + n * PCOLS + Q0 + h * 16;
#pragma unroll
        for (int d = 0; d < 16; ++d) qb[d * 128 + nl] = qr[d] * ISD;
        const float* qp = P + n * PCOLS + QP0 + h * 12;
        float q2 = 0.f;
#pragma unroll
        for (int pt = 0; pt < 4; ++pt) {
            float p0 = qp[pt * 3 + 0], p1 = qp[pt * 3 + 1], p2 = qp[pt * 3 + 2];
            float g0 = R00 * p0 + R01 * p1 + R02 * p2 + t0;
            float g1 = R10 * p0 + R11 * p1 + R12 * p2 + t1;
            float g2 = R20 * p0 + R21 * p1 + R22 * p2 + t2;
            qb[(16 + pt * 3 + 0) * 128 + nl] = g0 * (2.f * CC2);
            qb[(16 + pt * 3 + 1) * 128 + nl] = g1 * (2.f * CC2);
            qb[(16 + pt * 3 + 2) * 128 + nl] = g2 * (2.f * CC2);
            q2 += g0 * g0 + g1 * g1 + g2 * g2;
        }
        qcb[nl] = fmaf(-CC2, q2, -4.0f);
        const float* vr = P + n * PCOLS + V0 + h * 16;
#pragma unroll
        for (int d = 0; d < 16; ++d) vb[d * 128 + nl] = vr[d];
        const float* vp = P + n * PCOLS + VP0 + h * 12;
#pragma unroll
        for (int pt = 0; pt < 4; ++pt) {
            float p0 = vp[pt * 3 + 0], p1 = vp[pt * 3 + 1], p2 = vp[pt * 3 + 2];
            vb[(16 + pt * 3 + 0) * 128 + nl] = R00 * p0 + R01 * p1 + R02 * p2 + t0;
            vb[(16 + pt * 3 + 1) * 128 + nl] = R10 * p0 + R11 * p1 + R12 * p2 + t1;
            vb[(16 + pt * 3 + 2) * 128 + nl] = R20 * p0 + R21 * p1 + R22 * p2 + t2;
        }
    }
    __syncthreads();

    // write 2 packed tiles
    for (int u = tid; u < 2 * TILE_PAD; u += 256) {
        int tt = u / TILE_PAD, r = u % TILE_PAD;
        unsigned int val;
        if (r < OKV_V16) {
            int dp = r >> 6, j = r & 63;
            val = pkh(kb[(2 * dp) * 128 + tt * 64 + j], kb[(2 * dp + 1) * 128 + tt * 64 + j]);
        } else if (r < OKV_VP) {
            int idx = r - OKV_V16;
            int d = idx >> 5, jp = idx & 31;
            val = pkh(vb[d * 128 + tt * 64 + 2 * jp], vb[d * 128 + tt * 64 + 2 * jp + 1]);
        } else if (r < OKV_K2) {
            int idx = r - OKV_VP;
            int d = idx >> 6, j = idx & 63;
            val = __float_as_uint(vb[(16 + d) * 128 + tt * 64 + j]);
        } else if (r < TILE_U) {
            int j = r - OKV_K2;
            val = __float_as_uint(kb[28 * 128 + tt * 64 + j]);
        } else {
            val = 0u;
        }
        KVT[(h * 16 + nb * 2 + tt) * TILE_PAD + r] = val;
    }
    // Q' pairs
    for (int u = tid; u < 14 * 128; u += 256) {
        int dp = u >> 7, n2 = u & 127;
        Qh[(h * 14 + dp) * 1024 + nb * 128 + n2] =
            pkh(qb[(2 * dp) * 128 + n2], qb[(2 * dp + 1) * 128 + n2]);
    }
    if (tid < 32) *(float4*)&qcg[h * 1024 + nb * 128 + tid * 4] = *(float4*)&qcb[tid * 4];
}

// ---------- attention: fp16 logits + mixed PV, 2q x 8k, DMA staging ----------
// 1-D grid 768, XCD-colocating remap. 256 thr: ty=tid>>3 (32 x 2q), tx=tid&7 (8 x 8k).
__global__ __launch_bounds__(256, 2) void k_attn(
    const unsigned int* __restrict__ KVT, const unsigned int* __restrict__ Qh,
    const float* __restrict__ qcg, float* __restrict__ part)
{
    __shared__ unsigned int KV[2][TILE_PAD];
    __shared__ float red[29 * 64];
    int tid = threadIdx.x;
    int lane = tid & 63, w = tid >> 6;
    int ty = tid >> 3, tx = tid & 7;

    int bid = blockIdx.x;
    int xcd = bid & 7, slot = bid >> 3;
    int pair = xcd * 6 + (slot >> 4);
    int bx = slot & 15;
    int h = pair % H_NUM;
    int z = pair / H_NUM;

    int i0 = bx * 64;
    const unsigned int* KVbase = KVT + (h * 16 + z * 4) * TILE_PAD;

    // Q' pairs into registers (2 queries x 14 dp)
    f16x2 q0p[14], q1p[14];
#pragma unroll
    for (int dp = 0; dp < 14; ++dp) {
        q0p[dp] = as_h2(Qh[(h * 14 + dp) * 1024 + i0 + ty * 2 + 0]);
        q1p[dp] = as_h2(Qh[(h * 14 + dp) * 1024 + i0 + ty * 2 + 1]);
    }
    float qc[2];
    {
        float2 qcv = *(const float2*)&qcg[h * 1024 + i0 + ty * 2];
        qc[0] = qcv.x; qc[1] = qcv.y;
    }

    // 9 x 1KB DMA per tile; waves issue {3,2,2,2}
    int nst = (w == 0) ? 3 : 2;
    int gbase = (w == 0) ? 0 : 1 + w * 2;
#define STAGE(T) do { unsigned int* buf_ = KV[(T) & 1];                          \
        const unsigned int* sb_ = KVbase + (T) * TILE_PAD;                       \
        for (int m_ = 0; m_ < nst; ++m_) {                                       \
            int g_ = gbase + m_;                                                 \
            const unsigned int* src_ = sb_ + g_ * 256 + lane * 4;                \
            unsigned int* dst_ = buf_ + g_ * 256;                                \
            __builtin_amdgcn_global_load_lds(                                    \
                (const __attribute__((address_space(1))) void*)src_,             \
                (__attribute__((address_space(3))) void*)dst_, 16, 0, 0);        \
        } } while (0)

    STAGE(0);
    __syncthreads();

    float out[2][28] = {};
    float denom[2] = {};

    for (int t = 0; t < 4; ++t) {
        if (t < 3) STAGE(t + 1);
        const unsigned int* Kb = KV[t & 1];

        float s[2][8] = {};
#pragma unroll
        for (int dp = 0; dp < 14; ++dp) {
            uint4 a = *(const uint4*)&Kb[dp * 64 + tx * 8];
            uint4 b = *(const uint4*)&Kb[dp * 64 + tx * 8 + 4];
            unsigned int ka[8] = {a.x, a.y, a.z, a.w, b.x, b.y, b.z, b.w};
#pragma unroll
            for (int j = 0; j < 8; ++j) {
                s[0][j] = __builtin_amdgcn_fdot2(q0p[dp], as_h2(ka[j]), s[0][j], false);
                s[1][j] = __builtin_amdgcn_fdot2(q1p[dp], as_h2(ka[j]), s[1][j], false);
            }
        }
        const float* k2p = (const float*)&Kb[OKV_K2];
        float4 c0 = *(const float4*)&k2p[tx * 8];
        float4 c1 = *(const float4*)&k2p[tx * 8 + 4];
        float k2v[8] = {c0.x, c0.y, c0.z, c0.w, c1.x, c1.y, c1.z, c1.w};

        float p[2][8];
#pragma unroll
        for (int r = 0; r < 2; ++r) {
#pragma unroll
            for (int j = 0; j < 8; ++j) {
                p[r][j] = __expf(s[r][j] + k2v[j] + qc[r]);
                denom[r] += p[r][j];
            }
        }
        f16x2 pp[2][4];
#pragma unroll
        for (int r = 0; r < 2; ++r)
#pragma unroll
            for (int jp = 0; jp < 4; ++jp)
                pp[r][jp] = pkf(p[r][2 * jp], p[r][2 * jp + 1]);

        // V scalar (fp16 dot2), dims 0..15
#pragma unroll
        for (int d = 0; d < 16; ++d) {
            uint4 vv = *(const uint4*)&Kb[OKV_V16 + d * 32 + tx * 4];
#pragma unroll
            for (int r = 0; r < 2; ++r) {
                float acc = out[r][d];
                acc = __builtin_amdgcn_fdot2(pp[r][0], as_h2(vv.x), acc, false);
                acc = __builtin_amdgcn_fdot2(pp[r][1], as_h2(vv.y), acc, false);
                acc = __builtin_amdgcn_fdot2(pp[r][2], as_h2(vv.z), acc, false);
                acc = __builtin_amdgcn_fdot2(pp[r][3], as_h2(vv.w), acc, false);
                out[r][d] = acc;
            }
        }
        // V point (f32 fma), dims 16..27
#pragma unroll
        for (int d = 0; d < 12; ++d) {
            const float* vp = (const float*)&Kb[OKV_VP + d * 64];
            float4 v0 = *(const float4*)&vp[tx * 8];
            float4 v1 = *(const float4*)&vp[tx * 8 + 4];
            float va[8] = {v0.x, v0.y, v0.z, v0.w, v1.x, v1.y, v1.z, v1.w};
#pragma unroll
            for (int r = 0; r < 2; ++r) {
                float acc = out[r][16 + d];
#pragma unroll
                for (int j = 0; j < 8; ++j) acc = fmaf(p[r][j], va[j], acc);
                out[r][16 + d] = acc;
            }
        }
        __syncthreads();
    }

    // butterfly reduce across the 8 tx lanes
#pragma unroll
    for (int m = 1; m <= 4; m <<= 1) {
#pragma unroll
        for (int r = 0; r < 2; ++r) {
#pragma unroll
            for (int d = 0; d < 28; ++d) out[r][d] += __shfl_xor(out[r][d], m, 64);
            denom[r] += __shfl_xor(denom[r], m, 64);
        }
    }
    if (tx == 0) {
#pragma unroll
        for (int r = 0; r < 2; ++r) {
#pragma unroll
            for (int d = 0; d < 28; ++d) red[d * 64 + ty * 2 + r] = out[r][d];
            red[28 * 64 + ty * 2 + r] = denom[r];
        }
    }
    __syncthreads();
    for (int u = tid; u < 29 * 64; u += 256) {
        part[((z * H_NUM + h) * 29 + (u >> 6)) * N_TOK + i0 + (u & 63)] = red[u];
    }
}

// ---------- combine 4 partials, normalize, point-norm epilogue ----------
__global__ __launch_bounds__(256) void k_comb(
    const float* __restrict__ part, const float* __restrict__ rot,
    const float* __restrict__ trans, float* __restrict__ att)
{
    int t = blockIdx.x * 256 + threadIdx.x;
    int h = t >> 10, i = t & 1023;
    float v[29];
#pragma unroll
    for (int c = 0; c < 29; ++c) {
        float s = 0.f;
#pragma unroll
        for (int z = 0; z < NZ; ++z)
            s += part[((z * H_NUM + h) * 29 + c) * N_TOK + i];
        v[c] = s;
    }
    float inv = 1.f / v[28];
    float* arow = att + i * ATT_W;
#pragma unroll
    for (int d = 0; d < 16; ++d) arow[h * 16 + d] = v[d] * inv;
    float t0 = trans[i * 3 + 0], t1 = trans[i * 3 + 1], t2v = trans[i * 3 + 2];
    const float* R = rot + i * 9;
#pragma unroll
    for (int p = 0; p < 4; ++p) {
        float c0 = v[16 + p * 3 + 0] * inv - t0;
        float c1 = v[16 + p * 3 + 1] * inv - t1;
        float c2 = v[16 + p * 3 + 2] * inv - t2v;
        float l0 = R[0] * c0 + R[3] * c1 + R[6] * c2;
        float l1 = R[1] * c0 + R[4] * c1 + R[7] * c2;
        float l2 = R[2] * c0 + R[5] * c1 + R[8] * c2;
        arow[192 + h * 4 + p] = sqrtf(l0 * l0 + l1 * l1 + l2 * l2);
    }
}

// ---------- out GEMM: LDS-staged, reg-prefetch ----------
__global__ __launch_bounds__(256) void k_out(
    const float* __restrict__ att, const float* __restrict__ Wout,
    const float* __restrict__ bout, float* __restrict__ out)
{
    __shared__ float xs[64][17];
    __shared__ float wsh[16][64];
    int tid = threadIdx.x;
    int i0 = blockIdx.x * 64, c0 = blockIdx.y * 64;
    int lr = tid >> 2, lk = (tid & 3) * 4;
    int wr = tid >> 4, wc = (tid & 15) * 4;
    int ty = tid >> 4, tx = tid & 15;

    float4 xa = *(const float4*)(att + (i0 + lr) * ATT_W + lk);
    float4 wa = *(const float4*)(Wout + wr * C_DIM + c0 + wc);
    float acc[4][4] = {};

    for (int it = 0; it < 15; ++it) {
        xs[lr][lk + 0] = xa.x; xs[lr][lk + 1] = xa.y;
        xs[lr][lk + 2] = xa.z; xs[lr][lk + 3] = xa.w;
        *(float4*)&wsh[wr][wc] = wa;
        __syncthreads();
        if (it < 14) {
            xa = *(const float4*)(att + (i0 + lr) * ATT_W + (it + 1) * 16 + lk);
            wa = *(const float4*)(Wout + ((it + 1) * 16 + wr) * C_DIM + c0 + wc);
        }
#pragma unroll
        for (int kk = 0; kk < 16; ++kk) {
            float4 b = *(float4*)&wsh[kk][tx * 4];
            float a0 = xs[ty * 4 + 0][kk];
            float a1 = xs[ty * 4 + 1][kk];
            float a2 = xs[ty * 4 + 2][kk];
            float a3 = xs[ty * 4 + 3][kk];
            acc[0][0] = fmaf(a0, b.x, acc[0][0]); acc[0][1] = fmaf(a0, b.y, acc[0][1]);
            acc[0][2] = fmaf(a0, b.z, acc[0][2]); acc[0][3] = fmaf(a0, b.w, acc[0][3]);
            acc[1][0] = fmaf(a1, b.x, acc[1][0]); acc[1][1] = fmaf(a1, b.y, acc[1][1]);
            acc[1][2] = fmaf(a1, b.z, acc[1][2]); acc[1][3] = fmaf(a1, b.w, acc[1][3]);
            acc[2][0] = fmaf(a2, b.x, acc[2][0]); acc[2][1] = fmaf(a2, b.y, acc[2][1]);
            acc[2][2] = fmaf(a2, b.z, acc[2][2]); acc[2][3] = fmaf(a2, b.w, acc[2][3]);
            acc[3][0] = fmaf(a3, b.x, acc[3][0]); acc[3][1] = fmaf(a3, b.y, acc[3][1]);
            acc[3][2] = fmaf(a3, b.z, acc[3][2]); acc[3][3] = fmaf(a3, b.w, acc[3][3]);
        }
        __syncthreads();
    }
    float4 bb = *(const float4*)(bout + c0 + tx * 4);
#pragma unroll
    for (int r = 0; r < 4; ++r) {
        *(float4*)(out + (i0 + ty * 4 + r) * C_DIM + c0 + tx * 4) =
            make_float4(acc[r][0] + bb.x, acc[r][1] + bb.y, acc[r][2] + bb.z, acc[r][3] + bb.w);
    }
}

extern "C" void kernel_launch(void* const* d_in, const int* in_sizes, int n_in,
                              void* d_out, int out_size, void* d_ws, size_t ws_size,
                              hipStream_t stream) {
    const float* x     = (const float*)d_in[0];
    const float* rot   = (const float*)d_in[1];
    const float* trans = (const float*)d_in[2];
    const float* Wq    = (const float*)d_in[3];
    const float* Wk    = (const float*)d_in[4];
    const float* Wv    = (const float*)d_in[5];
    const float* Wqp   = (const float*)d_in[6];
    const float* Wkp   = (const float*)d_in[7];
    const float* Wvp   = (const float*)d_in[8];
    const float* Wout  = (const float*)d_in[9];
    const float* bout  = (const float*)d_in[10];
    float* out = (float*)d_out;

    float* ws = (float*)d_ws;
    float* P            = ws;                                 // 1024*1024
    unsigned int* KVT   = (unsigned int*)(P + N_TOK * PCOLS); // 12*16*2304 u32
    unsigned int* Qh    = KVT + H_NUM * 16 * TILE_PAD;        // 12*14*1024 u32
    float* qcg          = (float*)(Qh + H_NUM * 14 * 1024);   // 12*1024
    float* part         = qcg + H_NUM * 1024;                 // 4*12*29*1024
    float* att          = part + NZ * H_NUM * 29 * 1024;      // 1024*240

    k_proj<<<dim3(16, 16), 512, 0, stream>>>(x, Wq, Wk, Wv, Wqp, Wkp, Wvp, P);
    k_prep<<<dim3(8, 12), 256, 0, stream>>>(P, rot, trans, KVT, Qh, qcg);
    k_attn<<<768, 256, 0, stream>>>(KVT, Qh, qcg, part);
    k_comb<<<48, 256, 0, stream>>>(part, rot, trans, att);
    k_out<<<dim3(16, 6), 256, 0, stream>>>(att, Wout, bout, out);
}

// Round 19
// 79.915 us; speedup vs baseline: 1.4304x; 1.0155x over previous
//
#include <hip/hip_runtime.h>
#include <math.h>

#define N_TOK 1024
#define C_DIM 384
#define H_NUM 12
#define PCOLS 1024
#define Q0 0
#define K0 192
#define V0 384
#define QP0 576
#define KP0 720
#define VP0 864
#define ATT_W 240
#define COEF 0.11785113019775792f   // 0.5*sqrt(2/36)
#define ISD 0.25f
#define CC2 (COEF * ISD)            // 0.029462...
#define NZ 4
// packed KV tile (u32 units):
//   [0,896)      K' fp16 pairs   [14 dp][64 j]
//   [896,1408)   V scalar fp16   [16 d][32 jp]
//   [1408,2176)  V point f32     [12 d][64 j]
//   [2176,2240)  k2 f32          [64 j]
#define OKV_V16 896
#define OKV_VP 1408
#define OKV_K2 2176
#define TILE_U 2240
#define TILE_PAD 2304               // 9 KB per (h, 64-key tile): 9 x 1KB DMA

typedef _Float16 f16x2 __attribute__((ext_vector_type(2)));
typedef __fp16   p16x2 __attribute__((ext_vector_type(2)));
union U32H2 { unsigned int u; f16x2 f; p16x2 p; };
__device__ __forceinline__ f16x2 as_h2(unsigned int v) { U32H2 x; x.u = v; return x.f; }
__device__ __forceinline__ unsigned int pkh(float a, float b) {
    U32H2 x; x.p = __builtin_amdgcn_cvt_pkrtz(a, b); return x.u;
}
__device__ __forceinline__ f16x2 pkf(float a, float b) {
    U32H2 x; x.p = __builtin_amdgcn_cvt_pkrtz(a, b); return x.f;
}

// ---------- proj GEMM: fp16 operands in LDS, fdot2 inner loop ----------
__global__ __launch_bounds__(512) void k_proj(
    const float* __restrict__ x,
    const float* __restrict__ Wq, const float* __restrict__ Wk, const float* __restrict__ Wv,
    const float* __restrict__ Wqp, const float* __restrict__ Wkp, const float* __restrict__ Wvp,
    float* __restrict__ P)
{
    __shared__ unsigned int xs[8][72];
    __shared__ unsigned int wsh[8][64];
    int tid = threadIdx.x;
    int i0 = blockIdx.x * 64, c0 = blockIdx.y * 64;
    int sdp = tid & 7, slr = tid >> 3;
    int wdp = tid >> 6, wcc = tid & 63;
    int ty = tid >> 4, tx = tid & 15;

    int col = c0 + wcc;
    const float* Wb; int od, cb;
    if (col < 192)       { Wb = Wq;  od = 192; cb = col; }
    else if (col < 384)  { Wb = Wk;  od = 192; cb = col - 192; }
    else if (col < 576)  { Wb = Wv;  od = 192; cb = col - 384; }
    else if (col < 720)  { Wb = Wqp; od = 144; cb = col - 576; }
    else if (col < 864)  { Wb = Wkp; od = 144; cb = col - 720; }
    else if (col < 1008) { Wb = Wvp; od = 144; cb = col - 864; }
    else                 { Wb = nullptr; od = 0; cb = 0; }

    const float* xr = x + (i0 + slr) * C_DIM;

    float2 xa = *(const float2*)(xr + sdp * 2);
    float w0 = Wb ? Wb[(2 * wdp) * od + cb] : 0.f;
    float w1 = Wb ? Wb[(2 * wdp + 1) * od + cb] : 0.f;
    float acc[2][4] = {};

    for (int it = 0; it < 24; ++it) {
        xs[sdp][slr] = pkh(xa.x, xa.y);
        wsh[wdp][wcc] = pkh(w0, w1);
        __syncthreads();
        if (it < 23) {
            xa = *(const float2*)(xr + (it + 1) * 16 + sdp * 2);
            w0 = Wb ? Wb[((it + 1) * 16 + 2 * wdp) * od + cb] : 0.f;
            w1 = Wb ? Wb[((it + 1) * 16 + 2 * wdp + 1) * od + cb] : 0.f;
        }
#pragma unroll
        for (int dp = 0; dp < 8; ++dp) {
            uint2 au = *(const uint2*)&xs[dp][ty * 2];
            uint4 bu = *(const uint4*)&wsh[dp][tx * 4];
            unsigned int aa[2] = {au.x, au.y};
            unsigned int bb[4] = {bu.x, bu.y, bu.z, bu.w};
#pragma unroll
            for (int r = 0; r < 2; ++r)
#pragma unroll
                for (int c = 0; c < 4; ++c)
                    acc[r][c] = __builtin_amdgcn_fdot2(as_h2(aa[r]), as_h2(bb[c]), acc[r][c], false);
        }
        __syncthreads();
    }
#pragma unroll
    for (int r = 0; r < 2; ++r)
        *(float4*)(P + (i0 + ty * 2 + r) * PCOLS + c0 + tx * 4) =
            make_float4(acc[r][0], acc[r][1], acc[r][2], acc[r][3]);
}

// ---------- prep: 64 tokens/block, 4-way role split; writes one packed tile ----------
// grid (16 nb, 12 h), 256 thr.
__global__ __launch_bounds__(256) void k_prep(
    const float* __restrict__ P, const float* __restrict__ rot, const float* __restrict__ trans,
    unsigned int* __restrict__ KVT, unsigned int* __restrict__ Qh, float* __restrict__ qcg)
{
    __shared__ float kb[29 * 64];   // rows 0..27 K' dims, row 28 = -CC2*k2
    __shared__ float qb[28 * 64];
    __shared__ float vb[28 * 64];   // rows 0..15 V scalar, 16..27 V point
    __shared__ float qcb[64];
    int h = blockIdx.y, nb = blockIdx.x;
    int tid = threadIdx.x;
    int nl = tid & 63, role = tid >> 6;
    int n = nb * 64 + nl;
    const float* R = rot + n * 9;
    float R00 = R[0], R01 = R[1], R02 = R[2];
    float R10 = R[3], R11 = R[4], R12 = R[5];
    float R20 = R[6], R21 = R[7], R22 = R[8];
    float t0 = trans[n * 3 + 0], t1 = trans[n * 3 + 1], t2 = trans[n * 3 + 2];

    if (role == 0) {
        const float* kr = P + n * PCOLS + K0 + h * 16;
#pragma unroll
        for (int d = 0; d < 16; ++d) kb[d * 64 + nl] = kr[d];
        const float* kp = P + n * PCOLS + KP0 + h * 12;
        float k2 = 0.f;
#pragma unroll
        for (int pt = 0; pt < 4; ++pt) {
            float p0 = kp[pt * 3 + 0], p1 = kp[pt * 3 + 1], p2 = kp[pt * 3 + 2];
            float g0 = R00 * p0 + R01 * p1 + R02 * p2 + t0;
            float g1 = R10 * p0 + R11 * p1 + R12 * p2 + t1;
            float g2 = R20 * p0 + R21 * p1 + R22 * p2 + t2;
            kb[(16 + pt * 3 + 0) * 64 + nl] = g0;
            kb[(16 + pt * 3 + 1) * 64 + nl] = g1;
            kb[(16 + pt * 3 + 2) * 64 + nl] = g2;
            k2 += g0 * g0 + g1 * g1 + g2 * g2;
        }
        kb[28 * 64 + nl] = -CC2 * k2;
    } else if (role == 1) {
        const float* qr = P + n * PCOLS + Q0 + h * 16;
#pragma unroll
        for (int d = 0; d < 16; ++d) qb[d * 64 + nl] = qr[d] * ISD;
        const float* qp = P + n * PCOLS + QP0 + h * 12;
        float q2 = 0.f;
#pragma unroll
        for (int pt = 0; pt < 4; ++pt) {
            float p0 = qp[pt * 3 + 0], p1 = qp[pt * 3 + 1], p2 = qp[pt * 3 + 2];
            float g0 = R00 * p0 + R01 * p1 + R02 * p2 + t0;
            float g1 = R10 * p0 + R11 * p1 + R12 * p2 + t1;
            float g2 = R20 * p0 + R21 * p1 + R22 * p2 + t2;
            qb[(16 + pt * 3 + 0) * 64 + nl] = g0 * (2.f * CC2);
            qb[(16 + pt * 3 + 1) * 64 + nl] = g1 * (2.f * CC2);
            qb[(16 + pt * 3 + 2) * 64 + nl] = g2 * (2.f * CC2);
            q2 += g0 * g0 + g1 * g1 + g2 * g2;
        }
        qcb[nl] = fmaf(-CC2, q2, -4.0f);
    } else if (role == 2) {
        const float* vr = P + n * PCOLS + V0 + h * 16;
#pragma unroll
        for (int d = 0; d < 16; ++d) vb[d * 64 + nl] = vr[d];
    } else {
        const float* vp = P + n * PCOLS + VP0 + h * 12;
#pragma unroll
        for (int pt = 0; pt < 4; ++pt) {
            float p0 = vp[pt * 3 + 0], p1 = vp[pt * 3 + 1], p2 = vp[pt * 3 + 2];
            vb[(16 + pt * 3 + 0) * 64 + nl] = R00 * p0 + R01 * p1 + R02 * p2 + t0;
            vb[(16 + pt * 3 + 1) * 64 + nl] = R10 * p0 + R11 * p1 + R12 * p2 + t1;
            vb[(16 + pt * 3 + 2) * 64 + nl] = R20 * p0 + R21 * p1 + R22 * p2 + t2;
        }
    }
    __syncthreads();

    // write this block's packed tile
    unsigned int* dstT = KVT + (h * 16 + nb) * TILE_PAD;
    for (int r = tid; r < TILE_PAD; r += 256) {
        unsigned int val;
        if (r < OKV_V16) {
            int dp = r >> 6, j = r & 63;
            val = pkh(kb[(2 * dp) * 64 + j], kb[(2 * dp + 1) * 64 + j]);
        } else if (r < OKV_VP) {
            int idx = r - OKV_V16;
            int d = idx >> 5, jp = idx & 31;
            val = pkh(vb[d * 64 + 2 * jp], vb[d * 64 + 2 * jp + 1]);
        } else if (r < OKV_K2) {
            int idx = r - OKV_VP;
            int d = idx >> 6, j = idx & 63;
            val = __float_as_uint(vb[(16 + d) * 64 + j]);
        } else if (r < TILE_U) {
            int j = r - OKV_K2;
            val = __float_as_uint(kb[28 * 64 + j]);
        } else {
            val = 0u;
        }
        dstT[r] = val;
    }
    for (int u = tid; u < 14 * 64; u += 256) {
        int dp = u >> 6, n2 = u & 63;
        Qh[(h * 14 + dp) * 1024 + nb * 64 + n2] =
            pkh(qb[(2 * dp) * 64 + n2], qb[(2 * dp + 1) * 64 + n2]);
    }
    if (tid < 16) *(float4*)&qcg[h * 1024 + nb * 64 + tid * 4] = *(float4*)&qcb[tid * 4];
}

// ---------- attention: fp16 logits + mixed PV, 2q x 8k, DMA staging ----------
__global__ __launch_bounds__(256, 2) void k_attn(
    const unsigned int* __restrict__ KVT, const unsigned int* __restrict__ Qh,
    const float* __restrict__ qcg, float* __restrict__ part)
{
    __shared__ unsigned int KV[2][TILE_PAD];
    __shared__ float red[29 * 64];
    int tid = threadIdx.x;
    int lane = tid & 63, w = tid >> 6;
    int ty = tid >> 3, tx = tid & 7;

    int bid = blockIdx.x;
    int xcd = bid & 7, slot = bid >> 3;
    int pair = xcd * 6 + (slot >> 4);
    int bx = slot & 15;
    int h = pair % H_NUM;
    int z = pair / H_NUM;

    int i0 = bx * 64;
    const unsigned int* KVbase = KVT + (h * 16 + z * 4) * TILE_PAD;

    f16x2 q0p[14], q1p[14];
#pragma unroll
    for (int dp = 0; dp < 14; ++dp) {
        q0p[dp] = as_h2(Qh[(h * 14 + dp) * 1024 + i0 + ty * 2 + 0]);
        q1p[dp] = as_h2(Qh[(h * 14 + dp) * 1024 + i0 + ty * 2 + 1]);
    }
    float qc[2];
    {
        float2 qcv = *(const float2*)&qcg[h * 1024 + i0 + ty * 2];
        qc[0] = qcv.x; qc[1] = qcv.y;
    }

    int nst = (w == 0) ? 3 : 2;
    int gbase = (w == 0) ? 0 : 1 + w * 2;
#define STAGE(T) do { unsigned int* buf_ = KV[(T) & 1];                          \
        const unsigned int* sb_ = KVbase + (T) * TILE_PAD;                       \
        for (int m_ = 0; m_ < nst; ++m_) {                                       \
            int g_ = gbase + m_;                                                 \
            const unsigned int* src_ = sb_ + g_ * 256 + lane * 4;                \
            unsigned int* dst_ = buf_ + g_ * 256;                                \
            __builtin_amdgcn_global_load_lds(                                    \
                (const __attribute__((address_space(1))) void*)src_,             \
                (__attribute__((address_space(3))) void*)dst_, 16, 0, 0);        \
        } } while (0)

    STAGE(0);
    __syncthreads();

    float out[2][28] = {};
    float denom[2] = {};

    for (int t = 0; t < 4; ++t) {
        if (t < 3) STAGE(t + 1);
        const unsigned int* Kb = KV[t & 1];

        float s[2][8] = {};
#pragma unroll
        for (int dp = 0; dp < 14; ++dp) {
            uint4 a = *(const uint4*)&Kb[dp * 64 + tx * 8];
            uint4 b = *(const uint4*)&Kb[dp * 64 + tx * 8 + 4];
            unsigned int ka[8] = {a.x, a.y, a.z, a.w, b.x, b.y, b.z, b.w};
#pragma unroll
            for (int j = 0; j < 8; ++j) {
                s[0][j] = __builtin_amdgcn_fdot2(q0p[dp], as_h2(ka[j]), s[0][j], false);
                s[1][j] = __builtin_amdgcn_fdot2(q1p[dp], as_h2(ka[j]), s[1][j], false);
            }
        }
        const float* k2p = (const float*)&Kb[OKV_K2];
        float4 c0 = *(const float4*)&k2p[tx * 8];
        float4 c1 = *(const float4*)&k2p[tx * 8 + 4];
        float k2v[8] = {c0.x, c0.y, c0.z, c0.w, c1.x, c1.y, c1.z, c1.w};

        float p[2][8];
#pragma unroll
        for (int r = 0; r < 2; ++r) {
#pragma unroll
            for (int j = 0; j < 8; ++j) {
                p[r][j] = __expf(s[r][j] + k2v[j] + qc[r]);
                denom[r] += p[r][j];
            }
        }
        f16x2 pp[2][4];
#pragma unroll
        for (int r = 0; r < 2; ++r)
#pragma unroll
            for (int jp = 0; jp < 4; ++jp)
                pp[r][jp] = pkf(p[r][2 * jp], p[r][2 * jp + 1]);

#pragma unroll
        for (int d = 0; d < 16; ++d) {
            uint4 vv = *(const uint4*)&Kb[OKV_V16 + d * 32 + tx * 4];
#pragma unroll
            for (int r = 0; r < 2; ++r) {
                float acc = out[r][d];
                acc = __builtin_amdgcn_fdot2(pp[r][0], as_h2(vv.x), acc, false);
                acc = __builtin_amdgcn_fdot2(pp[r][1], as_h2(vv.y), acc, false);
                acc = __builtin_amdgcn_fdot2(pp[r][2], as_h2(vv.z), acc, false);
                acc = __builtin_amdgcn_fdot2(pp[r][3], as_h2(vv.w), acc, false);
                out[r][d] = acc;
            }
        }
#pragma unroll
        for (int d = 0; d < 12; ++d) {
            const float* vp = (const float*)&Kb[OKV_VP + d * 64];
            float4 v0 = *(const float4*)&vp[tx * 8];
            float4 v1 = *(const float4*)&vp[tx * 8 + 4];
            float va[8] = {v0.x, v0.y, v0.z, v0.w, v1.x, v1.y, v1.z, v1.w};
#pragma unroll
            for (int r = 0; r < 2; ++r) {
                float acc = out[r][16 + d];
#pragma unroll
                for (int j = 0; j < 8; ++j) acc = fmaf(p[r][j], va[j], acc);
                out[r][16 + d] = acc;
            }
        }
        __syncthreads();
    }

#pragma unroll
    for (int m = 1; m <= 4; m <<= 1) {
#pragma unroll
        for (int r = 0; r < 2; ++r) {
#pragma unroll
            for (int d = 0; d < 28; ++d) out[r][d] += __shfl_xor(out[r][d], m, 64);
            denom[r] += __shfl_xor(denom[r], m, 64);
        }
    }
    if (tx == 0) {
#pragma unroll
        for (int r = 0; r < 2; ++r) {
#pragma unroll
            for (int d = 0; d < 28; ++d) red[d * 64 + ty * 2 + r] = out[r][d];
            red[28 * 64 + ty * 2 + r] = denom[r];
        }
    }
    __syncthreads();
    for (int u = tid; u < 29 * 64; u += 256) {
        part[((z * H_NUM + h) * 29 + (u >> 6)) * N_TOK + i0 + (u & 63)] = red[u];
    }
}

// ---------- fused combine + out GEMM ----------
// grid (16,6), 256 thr. Phase A: build att rows in LDS from part; Phase B: GEMM.
__global__ __launch_bounds__(256) void k_outc(
    const float* __restrict__ part, const float* __restrict__ rot,
    const float* __restrict__ trans, const float* __restrict__ Wout,
    const float* __restrict__ bout, float* __restrict__ out)
{
    __shared__ float ab[64][241];
    __shared__ float den[64][13];
    __shared__ float wsh[16][64];
    int tid = threadIdx.x;
    int i0 = blockIdx.x * 64, c0 = blockIdx.y * 64;

    // phase 0: denominators (64 rows x 12 heads)
    for (int u = tid; u < 64 * 12; u += 256) {
        int r = u & 63, h = u >> 6;
        float s = 0.f;
#pragma unroll
        for (int z = 0; z < NZ; ++z)
            s += part[((z * H_NUM + h) * 29 + 28) * N_TOK + i0 + r];
        den[r][h] = 1.f / s;
    }
    __syncthreads();

    // phase 1: scalar columns (c = h*16+d, 192 of them)
    for (int u = tid; u < 192 * 64; u += 256) {
        int c = u >> 6, r = u & 63;
        int h = c >> 4, d = c & 15;
        float s = 0.f;
#pragma unroll
        for (int z = 0; z < NZ; ++z)
            s += part[((z * H_NUM + h) * 29 + d) * N_TOK + i0 + r];
        ab[r][c] = s * den[r][h];
    }
    // phase 2: point-norm columns (48 of them)
    for (int u = tid; u < 48 * 64; u += 256) {
        int pc = u >> 6, r = u & 63;
        int h = pc >> 2, p = pc & 3;
        int i = i0 + r;
        float inv = den[r][h];
        float v0 = 0.f, v1 = 0.f, v2 = 0.f;
#pragma unroll
        for (int z = 0; z < NZ; ++z) {
            int base = ((z * H_NUM + h) * 29 + 16 + p * 3) * N_TOK + i;
            v0 += part[base];
            v1 += part[base + N_TOK];
            v2 += part[base + 2 * N_TOK];
        }
        float c0f = v0 * inv - trans[i * 3 + 0];
        float c1f = v1 * inv - trans[i * 3 + 1];
        float c2f = v2 * inv - trans[i * 3 + 2];
        const float* R = rot + i * 9;
        float l0 = R[0] * c0f + R[3] * c1f + R[6] * c2f;
        float l1 = R[1] * c0f + R[4] * c1f + R[7] * c2f;
        float l2 = R[2] * c0f + R[5] * c1f + R[8] * c2f;
        ab[r][192 + pc] = sqrtf(l0 * l0 + l1 * l1 + l2 * l2);
    }

    int wr = tid >> 4, wc = (tid & 15) * 4;
    int ty = tid >> 4, tx = tid & 15;
    float4 wa = *(const float4*)(Wout + wr * C_DIM + c0 + wc);
    float acc[4][4] = {};
    __syncthreads();

    for (int it = 0; it < 15; ++it) {
        *(float4*)&wsh[wr][wc] = wa;
        __syncthreads();
        if (it < 14)
            wa = *(const float4*)(Wout + ((it + 1) * 16 + wr) * C_DIM + c0 + wc);
#pragma unroll
        for (int kk = 0; kk < 16; ++kk) {
            float4 b = *(float4*)&wsh[kk][tx * 4];
            float a0 = ab[ty * 4 + 0][it * 16 + kk];
            float a1 = ab[ty * 4 + 1][it * 16 + kk];
            float a2 = ab[ty * 4 + 2][it * 16 + kk];
            float a3 = ab[ty * 4 + 3][it * 16 + kk];
            acc[0][0] = fmaf(a0, b.x, acc[0][0]); acc[0][1] = fmaf(a0, b.y, acc[0][1]);
            acc[0][2] = fmaf(a0, b.z, acc[0][2]); acc[0][3] = fmaf(a0, b.w, acc[0][3]);
            acc[1][0] = fmaf(a1, b.x, acc[1][0]); acc[1][1] = fmaf(a1, b.y, acc[1][1]);
            acc[1][2] = fmaf(a1, b.z, acc[1][2]); acc[1][3] = fmaf(a1, b.w, acc[1][3]);
            acc[2][0] = fmaf(a2, b.x, acc[2][0]); acc[2][1] = fmaf(a2, b.y, acc[2][1]);
            acc[2][2] = fmaf(a2, b.z, acc[2][2]); acc[2][3] = fmaf(a2, b.w, acc[2][3]);
            acc[3][0] = fmaf(a3, b.x, acc[3][0]); acc[3][1] = fmaf(a3, b.y, acc[3][1]);
            acc[3][2] = fmaf(a3, b.z, acc[3][2]); acc[3][3] = fmaf(a3, b.w, acc[3][3]);
        }
        __syncthreads();
    }
    float4 bb = *(const float4*)(bout + c0 + tx * 4);
#pragma unroll
    for (int r = 0; r < 4; ++r) {
        *(float4*)(out + (i0 + ty * 4 + r) * C_DIM + c0 + tx * 4) =
            make_float4(acc[r][0] + bb.x, acc[r][1] + bb.y, acc[r][2] + bb.z, acc[r][3] + bb.w);
    }
}

extern "C" void kernel_launch(void* const* d_in, const int* in_sizes, int n_in,
                              void* d_out, int out_size, void* d_ws, size_t ws_size,
                              hipStream_t stream) {
    const float* x     = (const float*)d_in[0];
    const float* rot   = (const float*)d_in[1];
    const float* trans = (const float*)d_in[2];
    const float* Wq    = (const float*)d_in[3];
    const float* Wk    = (const float*)d_in[4];
    const float* Wv    = (const float*)d_in[5];
    const float* Wqp   = (const float*)d_in[6];
    const float* Wkp   = (const float*)d_in[7];
    const float* Wvp   = (const float*)d_in[8];
    const float* Wout  = (const float*)d_in[9];
    const float* bout  = (const float*)d_in[10];
    float* out = (float*)d_out;

    float* ws = (float*)d_ws;
    float* P            = ws;                                 // 1024*1024
    unsigned int* KVT   = (unsigned int*)(P + N_TOK * PCOLS); // 12*16*2304 u32
    unsigned int* Qh    = KVT + H_NUM * 16 * TILE_PAD;        // 12*14*1024 u32
    float* qcg          = (float*)(Qh + H_NUM * 14 * 1024);   // 12*1024
    float* part         = qcg + H_NUM * 1024;                 // 4*12*29*1024

    k_proj<<<dim3(16, 16), 512, 0, stream>>>(x, Wq, Wk, Wv, Wqp, Wkp, Wvp, P);
    k_prep<<<dim3(16, 12), 256, 0, stream>>>(P, rot, trans, KVT, Qh, qcg);
    k_attn<<<768, 256, 0, stream>>>(KVT, Qh, qcg, part);
    k_outc<<<dim3(16, 6), 256, 0, stream>>>(part, rot, trans, Wout, bout, out);
}